// Round 5
// baseline (508.508 us; speedup 1.0000x reference)
//
#include <hip/hip_runtime.h>
#include <hip/hip_bf16.h>

// Problem constants (from reference)
#define N_USERS    150000
#define N_ENTITIES 250000
#define NROWS      (N_ENTITIES + N_USERS)   // unified CSR rows
#define CHN        64
#define N_RELM1    16      // N_REL - 1
#define N_FACTORS  4
#define N_EDGES    1000000
#define NNZ_       1000000
#define NRECS      (N_EDGES + NNZ_)

__device__ __forceinline__ unsigned short f2bf(float f) {
    unsigned u = __float_as_uint(f);
    return (unsigned short)((u + 0x7fffu + ((u >> 16) & 1u)) >> 16);  // RNE
}
__device__ __forceinline__ float bf2f(unsigned short h) {
    return __uint_as_float(((unsigned)h) << 16);
}
__device__ __forceinline__ float4 bf4_to_f4(ushort4 v) {
    return make_float4(bf2f(v.x), bf2f(v.y), bf2f(v.z), bf2f(v.w));
}

// -------------------- small precompute: disen_weight + cor --------------------
__global__ void prep_small_kernel(const float* __restrict__ weight,   // [16][64]
                                  const float* __restrict__ att,      // [4][16]
                                  float* __restrict__ disenw,         // [4][64] out
                                  float* __restrict__ cor_out)        // scalar out
{
    int tid = threadIdx.x;           // 256 threads: f = tid>>6, ch = tid&63
    int f  = tid >> 6;
    int ch = tid & 63;

    float m = -1e30f;
    for (int r = 0; r < N_RELM1; ++r) m = fmaxf(m, att[f * N_RELM1 + r]);
    float ex[N_RELM1];
    float s = 0.f;
    for (int r = 0; r < N_RELM1; ++r) { ex[r] = expf(att[f * N_RELM1 + r] - m); s += ex[r]; }
    float inv = 1.f / s;
    float acc = 0.f;
    for (int r = 0; r < N_RELM1; ++r) acc += (ex[r] * inv) * weight[r * CHN + ch];
    disenw[f * CHN + ch] = acc;

    if (tid == 0) {
        float wn[N_FACTORS][N_RELM1];
        for (int i = 0; i < N_FACTORS; ++i) {
            float ss = 0.f;
            for (int r = 0; r < N_RELM1; ++r) { float v = att[i * N_RELM1 + r]; ss += v * v; }
            float innv = 1.f / sqrtf(ss);
            for (int r = 0; r < N_RELM1; ++r) wn[i][r] = att[i * N_RELM1 + r] * innv;
        }
        float cor = 0.f;
        for (int i = 0; i < N_FACTORS; ++i)
            for (int j = i + 1; j < N_FACTORS; ++j) {
                float d = 0.f;
                for (int r = 0; r < N_RELM1; ++r) d += wn[i][r] * wn[j][r];
                cor += d * d;
            }
        cor_out[0] = cor;
    }
}

// -------------------- f32 -> bf16 table conversion --------------------
__global__ __launch_bounds__(256) void conv_bf16_kernel(const float4* __restrict__ src,
                                                        ushort4* __restrict__ dst, int n4)
{
    int i = blockIdx.x * 256 + threadIdx.x;
    if (i >= n4) return;
    float4 v = src[i];
    dst[i] = make_ushort4(f2bf(v.x), f2bf(v.y), f2bf(v.z), f2bf(v.w));
}

// -------------------- unified count --------------------
__global__ __launch_bounds__(256) void count_all_kernel(const int* __restrict__ head,
                                                        const int* __restrict__ irow,
                                                        int* __restrict__ cnt)
{
    int i = blockIdx.x * 256 + threadIdx.x;
    if (i < N_EDGES) {
        atomicAdd(&cnt[head[i]], 1);
    } else {
        int j = i - N_EDGES;
        if (j < NNZ_) atomicAdd(&cnt[N_ENTITIES + irow[j]], 1);
    }
}

// -------------------- two-level exclusive scan --------------------
#define SCHUNK 512

__global__ __launch_bounds__(SCHUNK) void block_sum_kernel(const int* __restrict__ cnt,
                                                           int* __restrict__ bsum, int n)
{
    __shared__ int sdata[SCHUNK];
    int t = threadIdx.x;
    int i = blockIdx.x * SCHUNK + t;
    sdata[t] = (i < n) ? cnt[i] : 0;
    __syncthreads();
    for (int off = SCHUNK / 2; off > 0; off >>= 1) {
        if (t < off) sdata[t] += sdata[t + off];
        __syncthreads();
    }
    if (t == 0) bsum[blockIdx.x] = sdata[0];
}

__global__ __launch_bounds__(1024) void scan_small_kernel(int* __restrict__ bsum, int nb)
{
    __shared__ int a[1024], b[1024];
    int t = threadIdx.x;
    a[t] = (t < nb) ? bsum[t] : 0;
    __syncthreads();
    int* src = a; int* dst = b;
    for (int off = 1; off < 1024; off <<= 1) {
        dst[t] = src[t] + ((t >= off) ? src[t - off] : 0);
        __syncthreads();
        int* tm = src; src = dst; dst = tm;
    }
    int excl = (t == 0) ? 0 : src[t - 1];
    if (t < nb) bsum[t] = excl;
}

__global__ __launch_bounds__(SCHUNK) void scan_chunk_kernel(const int* __restrict__ cnt,
                                                            const int* __restrict__ bsum,
                                                            int* __restrict__ offs,
                                                            int* __restrict__ cur, int n)
{
    __shared__ int a[SCHUNK], b[SCHUNK];
    int t = threadIdx.x;
    int i = blockIdx.x * SCHUNK + t;
    a[t] = (i < n) ? cnt[i] : 0;
    __syncthreads();
    int* src = a; int* dst = b;
    for (int off = 1; off < SCHUNK; off <<= 1) {
        dst[t] = src[t] + ((t >= off) ? src[t - off] : 0);
        __syncthreads();
        int* tm = src; src = dst; dst = tm;
    }
    int excl = ((t == 0) ? 0 : src[t - 1]) + bsum[blockIdx.x];
    if (i < n) { offs[i] = excl; cur[i] = excl; }
}

// -------------------- unified slot scatter (atomicExch -> coherence point) ------
// Entity slots occupy [0, N_EDGES) of the unified slot space -> recsE (packed u32:
// tail | rel<<18). User slots occupy [N_EDGES, NRECS) -> recsU (u64: col | val<<32).
// atomicExch RMWs execute at the memory-side coherence point (shared across XCDs),
// so record lines aggregate there instead of bouncing between private L2s.
__global__ __launch_bounds__(256) void scatter_all_kernel(const int* __restrict__ head,
                                                          const int* __restrict__ tail,
                                                          const int* __restrict__ etype,
                                                          const int* __restrict__ irow,
                                                          const int* __restrict__ icol,
                                                          const float* __restrict__ val,
                                                          int* __restrict__ cur,
                                                          unsigned int* __restrict__ recsE,
                                                          unsigned long long* __restrict__ recsU)
{
    int i = blockIdx.x * 256 + threadIdx.x;
    if (i < N_EDGES) {
        int slot = atomicAdd(&cur[head[i]], 1);
        unsigned p = (unsigned)tail[i] | ((unsigned)(etype[i] - 1) << 18);
        atomicExch(&recsE[slot], p);
    } else {
        int j = i - N_EDGES;
        if (j < NNZ_) {
            int slot = atomicAdd(&cur[N_ENTITIES + irow[j]], 1) - N_EDGES;
            unsigned long long p = (unsigned)icol[j] |
                                   ((unsigned long long)(unsigned)__float_as_int(val[j]) << 32);
            atomicExch(&recsU[slot], p);
        }
    }
}

// -------------------- fused hop: 16 lanes per row, float4 per lane ------------
__global__ __launch_bounds__(256) void hop_kernel(const unsigned short* __restrict__ ebf,  // [N_ENTITIES][64] bf16
                                                  const float* __restrict__ u_src,
                                                  const unsigned int* __restrict__ recsE,
                                                  const unsigned long long* __restrict__ recsU,
                                                  const int* __restrict__ cnt,
                                                  const int* __restrict__ offs,
                                                  const float* __restrict__ weight,  // [16][64] f32
                                                  const float* __restrict__ latent,  // [4][64]
                                                  const float* __restrict__ disenw,  // [4][64]
                                                  const float* __restrict__ ent_resid,
                                                  const float* __restrict__ usr_resid,
                                                  unsigned short* __restrict__ ebf_new,  // nullptr: skip
                                                  float* __restrict__ u_new,             // nullptr: skip
                                                  float* __restrict__ out_ent,
                                                  float* __restrict__ out_usr)
{
    __shared__ float wl[N_RELM1 * CHN];
    for (int k = threadIdx.x; k < N_RELM1 * CHN; k += 256) wl[k] = weight[k];
    __syncthreads();

    unsigned idx = blockIdx.x * 256u + threadIdx.x;
    unsigned row = idx >> 4;          // 16 lanes per row
    int cg = idx & 15;                // channel group: floats [cg*4, cg*4+4)
    if (row >= NROWS) return;

    int n = cnt[row];

    if (row < N_ENTITIES) {
        int start = offs[row];
        float4 acc = make_float4(0.f, 0.f, 0.f, 0.f);
        int k = 0;
        for (; k + 4 <= n; k += 4) {
            unsigned p0 = recsE[start + k];
            unsigned p1 = recsE[start + k + 1];
            unsigned p2 = recsE[start + k + 2];
            unsigned p3 = recsE[start + k + 3];
            float4 g0 = bf4_to_f4(*(const ushort4*)(ebf + (size_t)(p0 & 0x3FFFF) * CHN + cg * 4));
            float4 g1 = bf4_to_f4(*(const ushort4*)(ebf + (size_t)(p1 & 0x3FFFF) * CHN + cg * 4));
            float4 g2 = bf4_to_f4(*(const ushort4*)(ebf + (size_t)(p2 & 0x3FFFF) * CHN + cg * 4));
            float4 g3 = bf4_to_f4(*(const ushort4*)(ebf + (size_t)(p3 & 0x3FFFF) * CHN + cg * 4));
            float4 w0 = *(const float4*)&wl[(p0 >> 18) * CHN + cg * 4];
            float4 w1 = *(const float4*)&wl[(p1 >> 18) * CHN + cg * 4];
            float4 w2 = *(const float4*)&wl[(p2 >> 18) * CHN + cg * 4];
            float4 w3 = *(const float4*)&wl[(p3 >> 18) * CHN + cg * 4];
            acc.x += g0.x * w0.x + g1.x * w1.x + g2.x * w2.x + g3.x * w3.x;
            acc.y += g0.y * w0.y + g1.y * w1.y + g2.y * w2.y + g3.y * w3.y;
            acc.z += g0.z * w0.z + g1.z * w1.z + g2.z * w2.z + g3.z * w3.z;
            acc.w += g0.w * w0.w + g1.w * w1.w + g2.w * w2.w + g3.w * w3.w;
        }
        for (; k < n; ++k) {
            unsigned p0 = recsE[start + k];
            float4 g0 = bf4_to_f4(*(const ushort4*)(ebf + (size_t)(p0 & 0x3FFFF) * CHN + cg * 4));
            float4 w0 = *(const float4*)&wl[(p0 >> 18) * CHN + cg * 4];
            acc.x += g0.x * w0.x; acc.y += g0.y * w0.y;
            acc.z += g0.z * w0.z; acc.w += g0.w * w0.w;
        }
        float d = (n > 0) ? (float)n : 1.f;
        float inv_d = 1.f / d;
        float4 x = make_float4(acc.x * inv_d, acc.y * inv_d, acc.z * inv_d, acc.w * inv_d);
        float ss = x.x * x.x + x.y * x.y + x.z * x.z + x.w * x.w;
        #pragma unroll
        for (int off = 8; off > 0; off >>= 1) ss += __shfl_xor(ss, off, 64);
        float innv = 1.f / fmaxf(sqrtf(ss), 1e-12f);
        float4 y = make_float4(x.x * innv, x.y * innv, x.z * innv, x.w * innv);
        if (ebf_new)
            *(ushort4*)(ebf_new + (size_t)row * CHN + cg * 4) =
                make_ushort4(f2bf(y.x), f2bf(y.y), f2bf(y.z), f2bf(y.w));
        float4 r = *(const float4*)&ent_resid[(size_t)row * CHN + cg * 4];
        *(float4*)&out_ent[(size_t)row * CHN + cg * 4] =
            make_float4(r.x + y.x, r.y + y.y, r.z + y.z, r.w + y.w);
    } else {
        unsigned ur = row - N_ENTITIES;
        int start = offs[row] - N_EDGES;
        float4 uo = *(const float4*)&u_src[(size_t)ur * CHN + cg * 4];

        // score = softmax(u_old @ latent^T) over 4 factors
        float dot[N_FACTORS];
        #pragma unroll
        for (int f = 0; f < N_FACTORS; ++f) {
            float4 lf = *(const float4*)&latent[f * CHN + cg * 4];
            float p = uo.x * lf.x + uo.y * lf.y + uo.z * lf.z + uo.w * lf.w;
            #pragma unroll
            for (int off = 8; off > 0; off >>= 1) p += __shfl_xor(p, off, 64);
            dot[f] = p;
        }
        float m = fmaxf(fmaxf(dot[0], dot[1]), fmaxf(dot[2], dot[3]));
        float es = 0.f;
        #pragma unroll
        for (int f = 0; f < N_FACTORS; ++f) { dot[f] = expf(dot[f] - m); es += dot[f]; }
        float sinv = 1.f / es;
        float4 mix = make_float4(0.f, 0.f, 0.f, 0.f);
        #pragma unroll
        for (int f = 0; f < N_FACTORS; ++f) {
            float sc = dot[f] * sinv;
            float4 dw = *(const float4*)&disenw[f * CHN + cg * 4];
            mix.x += sc * dw.x; mix.y += sc * dw.y;
            mix.z += sc * dw.z; mix.w += sc * dw.w;
        }

        float4 acc = make_float4(0.f, 0.f, 0.f, 0.f);
        int k = 0;
        for (; k + 4 <= n; k += 4) {
            unsigned long long q0 = recsU[start + k];
            unsigned long long q1 = recsU[start + k + 1];
            unsigned long long q2 = recsU[start + k + 2];
            unsigned long long q3 = recsU[start + k + 3];
            float4 g0 = bf4_to_f4(*(const ushort4*)(ebf + (size_t)(unsigned)(q0 & 0xFFFFFFFFu) * CHN + cg * 4));
            float4 g1 = bf4_to_f4(*(const ushort4*)(ebf + (size_t)(unsigned)(q1 & 0xFFFFFFFFu) * CHN + cg * 4));
            float4 g2 = bf4_to_f4(*(const ushort4*)(ebf + (size_t)(unsigned)(q2 & 0xFFFFFFFFu) * CHN + cg * 4));
            float4 g3 = bf4_to_f4(*(const ushort4*)(ebf + (size_t)(unsigned)(q3 & 0xFFFFFFFFu) * CHN + cg * 4));
            float v0 = __uint_as_float((unsigned)(q0 >> 32));
            float v1 = __uint_as_float((unsigned)(q1 >> 32));
            float v2 = __uint_as_float((unsigned)(q2 >> 32));
            float v3 = __uint_as_float((unsigned)(q3 >> 32));
            acc.x += g0.x * v0 + g1.x * v1 + g2.x * v2 + g3.x * v3;
            acc.y += g0.y * v0 + g1.y * v1 + g2.y * v2 + g3.y * v3;
            acc.z += g0.z * v0 + g1.z * v1 + g2.z * v2 + g3.z * v3;
            acc.w += g0.w * v0 + g1.w * v1 + g2.w * v2 + g3.w * v3;
        }
        for (; k < n; ++k) {
            unsigned long long q0 = recsU[start + k];
            float4 g0 = bf4_to_f4(*(const ushort4*)(ebf + (size_t)(unsigned)(q0 & 0xFFFFFFFFu) * CHN + cg * 4));
            float v0 = __uint_as_float((unsigned)(q0 >> 32));
            acc.x += g0.x * v0; acc.y += g0.y * v0;
            acc.z += g0.z * v0; acc.w += g0.w * v0;
        }
        float4 x = make_float4(acc.x * (1.f + mix.x), acc.y * (1.f + mix.y),
                               acc.z * (1.f + mix.z), acc.w * (1.f + mix.w));
        float ss = x.x * x.x + x.y * x.y + x.z * x.z + x.w * x.w;
        #pragma unroll
        for (int off = 8; off > 0; off >>= 1) ss += __shfl_xor(ss, off, 64);
        float innv = 1.f / fmaxf(sqrtf(ss), 1e-12f);
        float4 y = make_float4(x.x * innv, x.y * innv, x.z * innv, x.w * innv);
        if (u_new)
            *(float4*)&u_new[(size_t)ur * CHN + cg * 4] = y;
        float4 r = *(const float4*)&usr_resid[(size_t)ur * CHN + cg * 4];
        *(float4*)&out_usr[(size_t)ur * CHN + cg * 4] =
            make_float4(r.x + y.x, r.y + y.y, r.z + y.z, r.w + y.w);
    }
}

extern "C" void kernel_launch(void* const* d_in, const int* in_sizes, int n_in,
                              void* d_out, int out_size, void* d_ws, size_t ws_size,
                              hipStream_t stream) {
    const float* user_emb   = (const float*)d_in[0];
    const float* entity_emb = (const float*)d_in[1];
    const float* latent_emb = (const float*)d_in[2];
    const float* weight     = (const float*)d_in[3];
    const float* att        = (const float*)d_in[4];
    const float* inter_val  = (const float*)d_in[5];
    const int*   edge_index = (const int*)d_in[6];   // [2][N_EDGES]
    const int*   edge_type  = (const int*)d_in[7];
    const int*   inter_row  = (const int*)d_in[8];
    const int*   inter_col  = (const int*)d_in[9];

    const int* head = edge_index;
    const int* tail = edge_index + N_EDGES;

    float* out_ent = (float*)d_out;                              // [250000*64]
    float* out_usr = out_ent + (size_t)N_ENTITIES * CHN;         // [150000*64]
    float* out_cor = out_usr + (size_t)N_USERS * CHN;            // [1]

    // workspace layout
    unsigned short* ebf0  = (unsigned short*)d_ws;               // 16M bf16 (input entities)
    unsigned short* ebfA  = ebf0 + (size_t)N_ENTITIES * CHN;     // 16M bf16 (hop-1 entities)
    float* u      = (float*)(ebfA + (size_t)N_ENTITIES * CHN);   //  9,600,000 f
    float* disenw = u + (size_t)N_USERS * CHN;                   //        256 f
    unsigned long long* recsU = (unsigned long long*)(disenw + 256); // 1M u64 (8B-aligned: offset is even # floats)
    unsigned int* recsE = (unsigned int*)(recsU + NNZ_);         // 1M u32
    int*   cnt    = (int*)(recsE + N_EDGES);                     //    400,000 i
    int*   offs   = cnt + NROWS;                                 //    400,000 i
    int*   cur    = offs + NROWS;                                //    400,000 i
    int*   bs     = cur + NROWS;                                 //      1,024 i

    const int rec_blocks  = (NRECS + 255) / 256;                 // 7813
    const int scan_blocks = (NROWS + SCHUNK - 1) / SCHUNK;       // 782

    // ---- build unified CSR (entities rows [0,250k), users rows [250k,400k)) ----
    hipMemsetAsync(cnt, 0, (size_t)NROWS * sizeof(int), stream);
    count_all_kernel<<<rec_blocks, 256, 0, stream>>>(head, inter_row, cnt);
    block_sum_kernel<<<scan_blocks, SCHUNK, 0, stream>>>(cnt, bs, NROWS);
    scan_small_kernel<<<1, 1024, 0, stream>>>(bs, scan_blocks);
    scan_chunk_kernel<<<scan_blocks, SCHUNK, 0, stream>>>(cnt, bs, offs, cur, NROWS);
    scatter_all_kernel<<<rec_blocks, 256, 0, stream>>>(head, tail, edge_type,
                                                       inter_row, inter_col, inter_val,
                                                       cur, recsE, recsU);

    prep_small_kernel<<<1, 256, 0, stream>>>(weight, att, disenw, out_cor);

    // bf16 copy of input entity table
    {
        int n4 = N_ENTITIES * CHN / 4;                           // 4,000,000
        conv_bf16_kernel<<<(n4 + 255) / 256, 256, 0, stream>>>(
            (const float4*)entity_emb, (ushort4*)ebf0, n4);
    }

    const int hop_blocks = (NROWS * 16 + 255) / 256;             // 25000

    // ---- hop 1: gather from ebf0; residual base = inputs; emit ebfA + u ----
    hop_kernel<<<hop_blocks, 256, 0, stream>>>(ebf0, user_emb, recsE, recsU,
                                               cnt, offs, weight, latent_emb, disenw,
                                               entity_emb, user_emb,
                                               ebfA, u, out_ent, out_usr);

    // ---- hop 2: gather from ebfA; residual base = out (in-place add) ----
    hop_kernel<<<hop_blocks, 256, 0, stream>>>(ebfA, u, recsE, recsU,
                                               cnt, offs, weight, latent_emb, disenw,
                                               out_ent, out_usr,
                                               nullptr, nullptr, out_ent, out_usr);
}

// Round 6
// 404.763 us; speedup vs baseline: 1.2563x; 1.2563x over previous
//
#include <hip/hip_runtime.h>
#include <hip/hip_bf16.h>

// Problem constants (from reference)
#define N_USERS    150000
#define N_ENTITIES 250000
#define NROWS      (N_ENTITIES + N_USERS)   // unified CSR rows
#define CHN        64
#define N_RELM1    16      // N_REL - 1
#define N_FACTORS  4
#define N_EDGES    1000000
#define NNZ_       1000000
#define NRECS      (N_EDGES + NNZ_)

// bucket decomposition for the two-pass scatter
#define BROWS      4096                      // rows per coarse bucket
#define NB         98                        // ceil(NROWS / BROWS)
#define TILE_A     4096
#define TA_THREADS 512
#define ITEMS_A    8                         // TILE_A / TA_THREADS

__device__ __forceinline__ unsigned short f2bf(float f) {
    unsigned u = __float_as_uint(f);
    return (unsigned short)((u + 0x7fffu + ((u >> 16) & 1u)) >> 16);  // RNE
}
__device__ __forceinline__ float bf2f(unsigned short h) {
    return __uint_as_float(((unsigned)h) << 16);
}
__device__ __forceinline__ float4 bf4_to_f4(ushort4 v) {
    return make_float4(bf2f(v.x), bf2f(v.y), bf2f(v.z), bf2f(v.w));
}

// -------------------- small precompute: disen_weight + cor --------------------
__global__ void prep_small_kernel(const float* __restrict__ weight,   // [16][64]
                                  const float* __restrict__ att,      // [4][16]
                                  float* __restrict__ disenw,         // [4][64] out
                                  float* __restrict__ cor_out)        // scalar out
{
    int tid = threadIdx.x;           // 256 threads: f = tid>>6, ch = tid&63
    int f  = tid >> 6;
    int ch = tid & 63;

    float m = -1e30f;
    for (int r = 0; r < N_RELM1; ++r) m = fmaxf(m, att[f * N_RELM1 + r]);
    float ex[N_RELM1];
    float s = 0.f;
    for (int r = 0; r < N_RELM1; ++r) { ex[r] = expf(att[f * N_RELM1 + r] - m); s += ex[r]; }
    float inv = 1.f / s;
    float acc = 0.f;
    for (int r = 0; r < N_RELM1; ++r) acc += (ex[r] * inv) * weight[r * CHN + ch];
    disenw[f * CHN + ch] = acc;

    if (tid == 0) {
        float wn[N_FACTORS][N_RELM1];
        for (int i = 0; i < N_FACTORS; ++i) {
            float ss = 0.f;
            for (int r = 0; r < N_RELM1; ++r) { float v = att[i * N_RELM1 + r]; ss += v * v; }
            float innv = 1.f / sqrtf(ss);
            for (int r = 0; r < N_RELM1; ++r) wn[i][r] = att[i * N_RELM1 + r] * innv;
        }
        float cor = 0.f;
        for (int i = 0; i < N_FACTORS; ++i)
            for (int j = i + 1; j < N_FACTORS; ++j) {
                float d = 0.f;
                for (int r = 0; r < N_RELM1; ++r) d += wn[i][r] * wn[j][r];
                cor += d * d;
            }
        cor_out[0] = cor;
    }
}

// -------------------- f32 -> bf16 table conversion --------------------
__global__ __launch_bounds__(256) void conv_bf16_kernel(const float4* __restrict__ src,
                                                        ushort4* __restrict__ dst, int n4)
{
    int i = blockIdx.x * 256 + threadIdx.x;
    if (i >= n4) return;
    float4 v = src[i];
    dst[i] = make_ushort4(f2bf(v.x), f2bf(v.y), f2bf(v.z), f2bf(v.w));
}

// -------------------- unified count --------------------
__global__ __launch_bounds__(256) void count_all_kernel(const int* __restrict__ head,
                                                        const int* __restrict__ irow,
                                                        int* __restrict__ cnt)
{
    int i = blockIdx.x * 256 + threadIdx.x;
    if (i < N_EDGES) {
        atomicAdd(&cnt[head[i]], 1);
    } else {
        int j = i - N_EDGES;
        if (j < NNZ_) atomicAdd(&cnt[N_ENTITIES + irow[j]], 1);
    }
}

// -------------------- two-level exclusive scan --------------------
#define SCHUNK 512

__global__ __launch_bounds__(SCHUNK) void block_sum_kernel(const int* __restrict__ cnt,
                                                           int* __restrict__ bsum, int n)
{
    __shared__ int sdata[SCHUNK];
    int t = threadIdx.x;
    int i = blockIdx.x * SCHUNK + t;
    sdata[t] = (i < n) ? cnt[i] : 0;
    __syncthreads();
    for (int off = SCHUNK / 2; off > 0; off >>= 1) {
        if (t < off) sdata[t] += sdata[t + off];
        __syncthreads();
    }
    if (t == 0) bsum[blockIdx.x] = sdata[0];
}

__global__ __launch_bounds__(1024) void scan_small_kernel(int* __restrict__ bsum, int nb)
{
    __shared__ int a[1024], b[1024];
    int t = threadIdx.x;
    a[t] = (t < nb) ? bsum[t] : 0;
    __syncthreads();
    int* src = a; int* dst = b;
    for (int off = 1; off < 1024; off <<= 1) {
        dst[t] = src[t] + ((t >= off) ? src[t - off] : 0);
        __syncthreads();
        int* tm = src; src = dst; dst = tm;
    }
    int excl = (t == 0) ? 0 : src[t - 1];
    if (t < nb) bsum[t] = excl;
}

__global__ __launch_bounds__(SCHUNK) void scan_chunk_kernel(const int* __restrict__ cnt,
                                                            const int* __restrict__ bsum,
                                                            int* __restrict__ offs, int n)
{
    __shared__ int a[SCHUNK], b[SCHUNK];
    int t = threadIdx.x;
    int i = blockIdx.x * SCHUNK + t;
    a[t] = (i < n) ? cnt[i] : 0;
    __syncthreads();
    int* src = a; int* dst = b;
    for (int off = 1; off < SCHUNK; off <<= 1) {
        dst[t] = src[t] + ((t >= off) ? src[t - off] : 0);
        __syncthreads();
        int* tm = src; src = dst; dst = tm;
    }
    int excl = ((t == 0) ? 0 : src[t - 1]) + bsum[blockIdx.x];
    if (i < n) offs[i] = excl;
}

// -------------------- bucket region bases --------------------
__global__ void bucket_init_kernel(const int* __restrict__ offs,
                                   int* __restrict__ bstart,
                                   int* __restrict__ bcur)
{
    int t = threadIdx.x;   // 128 threads
    if (t < NB) {
        int v = offs[t * BROWS];
        bstart[t] = v;
        bcur[t] = v;
    }
    if (t == NB) bstart[NB] = NRECS;
}

// -------------------- Pass A: LDS-staged binning into coarse buckets ----------
// Record u64: rowlo(12b)<<50 | payload(50b).
//   entity payload: (rel 4b)<<18 | tail 18b
//   user payload:   (val f32)<<18 | col 18b
__global__ __launch_bounds__(TA_THREADS) void bin_pass_kernel(
    const int* __restrict__ head, const int* __restrict__ tail,
    const int* __restrict__ etype, const int* __restrict__ irow,
    const int* __restrict__ icol, const float* __restrict__ val,
    int* __restrict__ bcur, unsigned long long* __restrict__ binned)
{
    __shared__ int cntS[NB], startS[NB], gbase[NB];
    __shared__ unsigned long long buf[TILE_A];
    __shared__ unsigned char bk[TILE_A];

    int tid = threadIdx.x;
    if (tid < NB) cntS[tid] = 0;
    __syncthreads();

    int base = blockIdx.x * TILE_A;
    unsigned long long p[ITEMS_A];
    int bkt[ITEMS_A], rnk[ITEMS_A];
    #pragma unroll
    for (int j = 0; j < ITEMS_A; ++j) {
        int i = base + j * TA_THREADS + tid;
        bkt[j] = -1;
        if (i < NRECS) {
            int row; unsigned long long pay;
            if (i < N_EDGES) {
                row = head[i];
                pay = ((unsigned long long)(unsigned)(etype[i] - 1) << 18) | (unsigned)tail[i];
            } else {
                int jj = i - N_EDGES;
                row = N_ENTITIES + irow[jj];
                pay = ((unsigned long long)__float_as_uint(val[jj]) << 18) | (unsigned)icol[jj];
            }
            p[j] = pay | ((unsigned long long)(unsigned)(row & (BROWS - 1)) << 50);
            bkt[j] = row >> 12;
            rnk[j] = atomicAdd(&cntS[bkt[j]], 1);
        }
    }
    __syncthreads();
    if (tid == 0) {
        int s = 0;
        for (int b = 0; b < NB; ++b) { startS[b] = s; s += cntS[b]; }
    }
    if (tid < NB) gbase[tid] = atomicAdd(&bcur[tid], cntS[tid]);
    __syncthreads();

    #pragma unroll
    for (int j = 0; j < ITEMS_A; ++j) {
        if (bkt[j] >= 0) {
            int s = startS[bkt[j]] + rnk[j];
            buf[s] = p[j];
            bk[s] = (unsigned char)bkt[j];
        }
    }
    __syncthreads();

    int total = startS[NB - 1] + cntS[NB - 1];
    for (int s = tid; s < total; s += TA_THREADS) {
        int b = bk[s];
        binned[gbase[b] + (s - startS[b])] = buf[s];
    }
}

// -------------------- Pass B: exclusive intra-bucket scatter to CSR slots ------
__global__ __launch_bounds__(512) void bucket_scatter_kernel(
    const unsigned long long* __restrict__ binned,
    const int* __restrict__ bstart, const int* __restrict__ offs,
    unsigned int* __restrict__ recsE, unsigned long long* __restrict__ recsU)
{
    __shared__ int rowcnt[BROWS];
    int tid = threadIdx.x;
    for (int r = tid; r < BROWS; r += 512) rowcnt[r] = 0;
    __syncthreads();

    int b = blockIdx.x;
    int r0 = b * BROWS;
    int s0 = bstart[b], s1 = bstart[b + 1];
    for (int i = s0 + tid; i < s1; i += 512) {
        unsigned long long p = binned[i];
        int rowlo = (int)(p >> 50) & (BROWS - 1);
        int rank = atomicAdd(&rowcnt[rowlo], 1);
        int row = r0 + rowlo;
        int slot = offs[row] + rank;
        unsigned long long pay = p & ((1ull << 50) - 1);
        if (row < N_ENTITIES) recsE[slot] = (unsigned)pay;
        else recsU[slot - N_EDGES] = pay;
    }
}

// -------------------- fused hop: 16 lanes per row, float4 per lane ------------
__global__ __launch_bounds__(256) void hop_kernel(const unsigned short* __restrict__ ebf,  // [N_ENTITIES][64] bf16
                                                  const float* __restrict__ u_src,
                                                  const unsigned int* __restrict__ recsE,
                                                  const unsigned long long* __restrict__ recsU,
                                                  const int* __restrict__ cnt,
                                                  const int* __restrict__ offs,
                                                  const float* __restrict__ weight,  // [16][64] f32
                                                  const float* __restrict__ latent,  // [4][64]
                                                  const float* __restrict__ disenw,  // [4][64]
                                                  const float* __restrict__ ent_resid,
                                                  const float* __restrict__ usr_resid,
                                                  unsigned short* __restrict__ ebf_new,  // nullptr: skip
                                                  float* __restrict__ u_new,             // nullptr: skip
                                                  float* __restrict__ out_ent,
                                                  float* __restrict__ out_usr)
{
    __shared__ float wl[N_RELM1 * CHN];
    for (int k = threadIdx.x; k < N_RELM1 * CHN; k += 256) wl[k] = weight[k];
    __syncthreads();

    unsigned idx = blockIdx.x * 256u + threadIdx.x;
    unsigned row = idx >> 4;          // 16 lanes per row
    int cg = idx & 15;                // channel group: floats [cg*4, cg*4+4)
    if (row >= NROWS) return;

    int n = cnt[row];

    if (row < N_ENTITIES) {
        int start = offs[row];
        float4 acc = make_float4(0.f, 0.f, 0.f, 0.f);
        int k = 0;
        for (; k + 4 <= n; k += 4) {
            unsigned p0 = recsE[start + k];
            unsigned p1 = recsE[start + k + 1];
            unsigned p2 = recsE[start + k + 2];
            unsigned p3 = recsE[start + k + 3];
            float4 g0 = bf4_to_f4(*(const ushort4*)(ebf + (size_t)(p0 & 0x3FFFF) * CHN + cg * 4));
            float4 g1 = bf4_to_f4(*(const ushort4*)(ebf + (size_t)(p1 & 0x3FFFF) * CHN + cg * 4));
            float4 g2 = bf4_to_f4(*(const ushort4*)(ebf + (size_t)(p2 & 0x3FFFF) * CHN + cg * 4));
            float4 g3 = bf4_to_f4(*(const ushort4*)(ebf + (size_t)(p3 & 0x3FFFF) * CHN + cg * 4));
            float4 w0 = *(const float4*)&wl[(p0 >> 18) * CHN + cg * 4];
            float4 w1 = *(const float4*)&wl[(p1 >> 18) * CHN + cg * 4];
            float4 w2 = *(const float4*)&wl[(p2 >> 18) * CHN + cg * 4];
            float4 w3 = *(const float4*)&wl[(p3 >> 18) * CHN + cg * 4];
            acc.x += g0.x * w0.x + g1.x * w1.x + g2.x * w2.x + g3.x * w3.x;
            acc.y += g0.y * w0.y + g1.y * w1.y + g2.y * w2.y + g3.y * w3.y;
            acc.z += g0.z * w0.z + g1.z * w1.z + g2.z * w2.z + g3.z * w3.z;
            acc.w += g0.w * w0.w + g1.w * w1.w + g2.w * w2.w + g3.w * w3.w;
        }
        for (; k < n; ++k) {
            unsigned p0 = recsE[start + k];
            float4 g0 = bf4_to_f4(*(const ushort4*)(ebf + (size_t)(p0 & 0x3FFFF) * CHN + cg * 4));
            float4 w0 = *(const float4*)&wl[(p0 >> 18) * CHN + cg * 4];
            acc.x += g0.x * w0.x; acc.y += g0.y * w0.y;
            acc.z += g0.z * w0.z; acc.w += g0.w * w0.w;
        }
        float d = (n > 0) ? (float)n : 1.f;
        float inv_d = 1.f / d;
        float4 x = make_float4(acc.x * inv_d, acc.y * inv_d, acc.z * inv_d, acc.w * inv_d);
        float ss = x.x * x.x + x.y * x.y + x.z * x.z + x.w * x.w;
        #pragma unroll
        for (int off = 8; off > 0; off >>= 1) ss += __shfl_xor(ss, off, 64);
        float innv = 1.f / fmaxf(sqrtf(ss), 1e-12f);
        float4 y = make_float4(x.x * innv, x.y * innv, x.z * innv, x.w * innv);
        if (ebf_new)
            *(ushort4*)(ebf_new + (size_t)row * CHN + cg * 4) =
                make_ushort4(f2bf(y.x), f2bf(y.y), f2bf(y.z), f2bf(y.w));
        float4 r = *(const float4*)&ent_resid[(size_t)row * CHN + cg * 4];
        *(float4*)&out_ent[(size_t)row * CHN + cg * 4] =
            make_float4(r.x + y.x, r.y + y.y, r.z + y.z, r.w + y.w);
    } else {
        unsigned ur = row - N_ENTITIES;
        int start = offs[row] - N_EDGES;
        float4 uo = *(const float4*)&u_src[(size_t)ur * CHN + cg * 4];

        // score = softmax(u_old @ latent^T) over 4 factors
        float dot[N_FACTORS];
        #pragma unroll
        for (int f = 0; f < N_FACTORS; ++f) {
            float4 lf = *(const float4*)&latent[f * CHN + cg * 4];
            float p = uo.x * lf.x + uo.y * lf.y + uo.z * lf.z + uo.w * lf.w;
            #pragma unroll
            for (int off = 8; off > 0; off >>= 1) p += __shfl_xor(p, off, 64);
            dot[f] = p;
        }
        float m = fmaxf(fmaxf(dot[0], dot[1]), fmaxf(dot[2], dot[3]));
        float es = 0.f;
        #pragma unroll
        for (int f = 0; f < N_FACTORS; ++f) { dot[f] = expf(dot[f] - m); es += dot[f]; }
        float sinv = 1.f / es;
        float4 mix = make_float4(0.f, 0.f, 0.f, 0.f);
        #pragma unroll
        for (int f = 0; f < N_FACTORS; ++f) {
            float sc = dot[f] * sinv;
            float4 dw = *(const float4*)&disenw[f * CHN + cg * 4];
            mix.x += sc * dw.x; mix.y += sc * dw.y;
            mix.z += sc * dw.z; mix.w += sc * dw.w;
        }

        float4 acc = make_float4(0.f, 0.f, 0.f, 0.f);
        int k = 0;
        for (; k + 4 <= n; k += 4) {
            unsigned long long q0 = recsU[start + k];
            unsigned long long q1 = recsU[start + k + 1];
            unsigned long long q2 = recsU[start + k + 2];
            unsigned long long q3 = recsU[start + k + 3];
            float4 g0 = bf4_to_f4(*(const ushort4*)(ebf + (size_t)(q0 & 0x3FFFFu) * CHN + cg * 4));
            float4 g1 = bf4_to_f4(*(const ushort4*)(ebf + (size_t)(q1 & 0x3FFFFu) * CHN + cg * 4));
            float4 g2 = bf4_to_f4(*(const ushort4*)(ebf + (size_t)(q2 & 0x3FFFFu) * CHN + cg * 4));
            float4 g3 = bf4_to_f4(*(const ushort4*)(ebf + (size_t)(q3 & 0x3FFFFu) * CHN + cg * 4));
            float v0 = __uint_as_float((unsigned)(q0 >> 18));
            float v1 = __uint_as_float((unsigned)(q1 >> 18));
            float v2 = __uint_as_float((unsigned)(q2 >> 18));
            float v3 = __uint_as_float((unsigned)(q3 >> 18));
            acc.x += g0.x * v0 + g1.x * v1 + g2.x * v2 + g3.x * v3;
            acc.y += g0.y * v0 + g1.y * v1 + g2.y * v2 + g3.y * v3;
            acc.z += g0.z * v0 + g1.z * v1 + g2.z * v2 + g3.z * v3;
            acc.w += g0.w * v0 + g1.w * v1 + g2.w * v2 + g3.w * v3;
        }
        for (; k < n; ++k) {
            unsigned long long q0 = recsU[start + k];
            float4 g0 = bf4_to_f4(*(const ushort4*)(ebf + (size_t)(q0 & 0x3FFFFu) * CHN + cg * 4));
            float v0 = __uint_as_float((unsigned)(q0 >> 18));
            acc.x += g0.x * v0; acc.y += g0.y * v0;
            acc.z += g0.z * v0; acc.w += g0.w * v0;
        }
        float4 x = make_float4(acc.x * (1.f + mix.x), acc.y * (1.f + mix.y),
                               acc.z * (1.f + mix.z), acc.w * (1.f + mix.w));
        float ss = x.x * x.x + x.y * x.y + x.z * x.z + x.w * x.w;
        #pragma unroll
        for (int off = 8; off > 0; off >>= 1) ss += __shfl_xor(ss, off, 64);
        float innv = 1.f / fmaxf(sqrtf(ss), 1e-12f);
        float4 y = make_float4(x.x * innv, x.y * innv, x.z * innv, x.w * innv);
        if (u_new)
            *(float4*)&u_new[(size_t)ur * CHN + cg * 4] = y;
        float4 r = *(const float4*)&usr_resid[(size_t)ur * CHN + cg * 4];
        *(float4*)&out_usr[(size_t)ur * CHN + cg * 4] =
            make_float4(r.x + y.x, r.y + y.y, r.z + y.z, r.w + y.w);
    }
}

extern "C" void kernel_launch(void* const* d_in, const int* in_sizes, int n_in,
                              void* d_out, int out_size, void* d_ws, size_t ws_size,
                              hipStream_t stream) {
    const float* user_emb   = (const float*)d_in[0];
    const float* entity_emb = (const float*)d_in[1];
    const float* latent_emb = (const float*)d_in[2];
    const float* weight     = (const float*)d_in[3];
    const float* att        = (const float*)d_in[4];
    const float* inter_val  = (const float*)d_in[5];
    const int*   edge_index = (const int*)d_in[6];   // [2][N_EDGES]
    const int*   edge_type  = (const int*)d_in[7];
    const int*   inter_row  = (const int*)d_in[8];
    const int*   inter_col  = (const int*)d_in[9];

    const int* head = edge_index;
    const int* tail = edge_index + N_EDGES;

    float* out_ent = (float*)d_out;                              // [250000*64]
    float* out_usr = out_ent + (size_t)N_ENTITIES * CHN;         // [150000*64]
    float* out_cor = out_usr + (size_t)N_USERS * CHN;            // [1]

    // workspace layout (all sub-offsets are multiples of 8 bytes)
    unsigned short* ebf0  = (unsigned short*)d_ws;               // 16M bf16
    unsigned short* ebfA  = ebf0 + (size_t)N_ENTITIES * CHN;     // 16M bf16
    float* u      = (float*)(ebfA + (size_t)N_ENTITIES * CHN);   //  9,600,000 f
    float* disenw = u + (size_t)N_USERS * CHN;                   //        256 f
    unsigned long long* recsU  = (unsigned long long*)(disenw + 256); // 1M u64
    unsigned long long* binned = recsU + NNZ_;                   //  2M u64
    unsigned int* recsE = (unsigned int*)(binned + NRECS);       //  1M u32
    int*   cnt    = (int*)(recsE + N_EDGES);                     //    400,000 i
    int*   offs   = cnt + NROWS;                                 //    400,000 i
    int*   bs     = offs + NROWS;                                //      1,024 i
    int*   bstart = bs + 1024;                                   //      NB+1 i
    int*   bcur   = bstart + (NB + 1);                           //        NB i

    const int rec_blocks  = (NRECS + 255) / 256;                 // 7813
    const int scan_blocks = (NROWS + SCHUNK - 1) / SCHUNK;       // 782
    const int binA_blocks = (NRECS + TILE_A - 1) / TILE_A;       // 489

    // ---- per-row counts + CSR offsets ----
    hipMemsetAsync(cnt, 0, (size_t)NROWS * sizeof(int), stream);
    count_all_kernel<<<rec_blocks, 256, 0, stream>>>(head, inter_row, cnt);
    block_sum_kernel<<<scan_blocks, SCHUNK, 0, stream>>>(cnt, bs, NROWS);
    scan_small_kernel<<<1, 1024, 0, stream>>>(bs, scan_blocks);
    scan_chunk_kernel<<<scan_blocks, SCHUNK, 0, stream>>>(cnt, bs, offs, NROWS);

    // ---- two-pass scatter: bin into coarse buckets, then exclusive intra-bucket scatter
    bucket_init_kernel<<<1, 128, 0, stream>>>(offs, bstart, bcur);
    bin_pass_kernel<<<binA_blocks, TA_THREADS, 0, stream>>>(head, tail, edge_type,
                                                            inter_row, inter_col, inter_val,
                                                            bcur, binned);
    bucket_scatter_kernel<<<NB, 512, 0, stream>>>(binned, bstart, offs, recsE, recsU);

    prep_small_kernel<<<1, 256, 0, stream>>>(weight, att, disenw, out_cor);

    // bf16 copy of input entity table
    {
        int n4 = N_ENTITIES * CHN / 4;                           // 4,000,000
        conv_bf16_kernel<<<(n4 + 255) / 256, 256, 0, stream>>>(
            (const float4*)entity_emb, (ushort4*)ebf0, n4);
    }

    const int hop_blocks = (NROWS * 16 + 255) / 256;             // 25000

    // ---- hop 1: gather from ebf0; residual base = inputs; emit ebfA + u ----
    hop_kernel<<<hop_blocks, 256, 0, stream>>>(ebf0, user_emb, recsE, recsU,
                                               cnt, offs, weight, latent_emb, disenw,
                                               entity_emb, user_emb,
                                               ebfA, u, out_ent, out_usr);

    // ---- hop 2: gather from ebfA; residual base = out (in-place add) ----
    hop_kernel<<<hop_blocks, 256, 0, stream>>>(ebfA, u, recsE, recsU,
                                               cnt, offs, weight, latent_emb, disenw,
                                               out_ent, out_usr,
                                               nullptr, nullptr, out_ent, out_usr);
}

// Round 8
// 256.592 us; speedup vs baseline: 1.9818x; 1.5775x over previous
//
#include <hip/hip_runtime.h>
#include <hip/hip_bf16.h>

// Problem constants (from reference)
#define N_USERS    150000
#define N_ENTITIES 250000
#define CHN        64
#define N_RELM1    16
#define N_FACTORS  4
#define N_EDGES    1000000
#define NNZ_       1000000
#define NRECS      (N_EDGES + NNZ_)

// fixed-capacity bucket decomposition (row-space: entities [0,250000), users [USR0, USR0+150000))
#define BROWS      1024
#define RCAP       8192                       // binned-region capacity per bucket (u64 records)
#define RCAP_OUT   8192                       // output recsE/recsU region capacity per bucket
#define EBUCKETS   245                        // ceil(250000/1024) -> entity buckets 0..244
#define USR0       (EBUCKETS * BROWS)         // 250880
#define ROWS_EFF   (USR0 + N_USERS)           // 400880
#define NB         392                        // ceil(ROWS_EFF/1024)
#define TILE_A     4096
#define TA_THREADS 512
#define ITEMS_A    8

typedef float vf4 __attribute__((ext_vector_type(4)));   // Clang vector: ok for nontemporal builtins

__device__ __forceinline__ unsigned short f2bf(float f) {
    unsigned u = __float_as_uint(f);
    return (unsigned short)((u + 0x7fffu + ((u >> 16) & 1u)) >> 16);  // RNE
}

// -------------------- prep: disen_weight + cor + bucket cursor init --------------------
__global__ __launch_bounds__(512) void prep_small_kernel(const float* __restrict__ weight,   // [16][64]
                                  const float* __restrict__ att,      // [4][16]
                                  float* __restrict__ disenw,         // [4][64] out
                                  float* __restrict__ cor_out,        // scalar out
                                  int* __restrict__ bcur)
{
    int tid = threadIdx.x;
    if (tid < NB) bcur[tid] = tid * RCAP;

    if (tid < 256) {
        int f  = tid >> 6;
        int ch = tid & 63;
        float m = -1e30f;
        for (int r = 0; r < N_RELM1; ++r) m = fmaxf(m, att[f * N_RELM1 + r]);
        float ex[N_RELM1];
        float s = 0.f;
        for (int r = 0; r < N_RELM1; ++r) { ex[r] = expf(att[f * N_RELM1 + r] - m); s += ex[r]; }
        float inv = 1.f / s;
        float acc = 0.f;
        for (int r = 0; r < N_RELM1; ++r) acc += (ex[r] * inv) * weight[r * CHN + ch];
        disenw[f * CHN + ch] = acc;
    }

    if (tid == 0) {
        float wn[N_FACTORS][N_RELM1];
        for (int i = 0; i < N_FACTORS; ++i) {
            float ss = 0.f;
            for (int r = 0; r < N_RELM1; ++r) { float v = att[i * N_RELM1 + r]; ss += v * v; }
            float innv = 1.f / sqrtf(ss);
            for (int r = 0; r < N_RELM1; ++r) wn[i][r] = att[i * N_RELM1 + r] * innv;
        }
        float cor = 0.f;
        for (int i = 0; i < N_FACTORS; ++i)
            for (int j = i + 1; j < N_FACTORS; ++j) {
                float d = 0.f;
                for (int r = 0; r < N_RELM1; ++r) d += wn[i][r] * wn[j][r];
                cor += d * d;
            }
        cor_out[0] = cor;
    }
}

// -------------------- f32 -> bf16 table conversion --------------------
__global__ __launch_bounds__(256) void conv_bf16_kernel(const float4* __restrict__ src,
                                                        ushort4* __restrict__ dst, int n4)
{
    int i = blockIdx.x * 256 + threadIdx.x;
    if (i >= n4) return;
    float4 v = src[i];
    dst[i] = make_ushort4(f2bf(v.x), f2bf(v.y), f2bf(v.z), f2bf(v.w));
}

// -------------------- Pass A: LDS-staged binning into fixed-capacity buckets ----
// Record u64: rowlo(10b)<<50 | payload(50b).
//   entity payload: (rel 4b)<<18 | tail 18b
//   user payload:   (val f32)<<18 | col 18b
__global__ __launch_bounds__(TA_THREADS) void bin_pass_kernel(
    const int* __restrict__ head, const int* __restrict__ tail,
    const int* __restrict__ etype, const int* __restrict__ irow,
    const int* __restrict__ icol, const float* __restrict__ val,
    int* __restrict__ bcur, unsigned long long* __restrict__ binned)
{
    __shared__ int cntS[NB], startS[NB], gbase[NB];
    __shared__ unsigned long long buf[TILE_A];
    __shared__ unsigned short bk[TILE_A];

    int tid = threadIdx.x;
    if (tid < NB) cntS[tid] = 0;
    __syncthreads();

    int base = blockIdx.x * TILE_A;
    unsigned long long p[ITEMS_A];
    int bkt[ITEMS_A], rnk[ITEMS_A];
    #pragma unroll
    for (int j = 0; j < ITEMS_A; ++j) {
        int i = base + j * TA_THREADS + tid;
        bkt[j] = -1;
        if (i < NRECS) {
            int row; unsigned long long pay;
            if (i < N_EDGES) {
                row = head[i];
                pay = ((unsigned long long)(unsigned)(etype[i] - 1) << 18) | (unsigned)tail[i];
            } else {
                int jj = i - N_EDGES;
                row = USR0 + irow[jj];
                pay = ((unsigned long long)__float_as_uint(val[jj]) << 18) | (unsigned)icol[jj];
            }
            p[j] = pay | ((unsigned long long)(unsigned)(row & (BROWS - 1)) << 50);
            bkt[j] = row >> 10;
            rnk[j] = atomicAdd(&cntS[bkt[j]], 1);
        }
    }
    __syncthreads();
    if (tid == 0) {
        int s = 0;
        for (int b = 0; b < NB; ++b) { startS[b] = s; s += cntS[b]; }
    }
    __syncthreads();
    if (tid < NB && cntS[tid] > 0) gbase[tid] = atomicAdd(&bcur[tid], cntS[tid]);
    __syncthreads();

    #pragma unroll
    for (int j = 0; j < ITEMS_A; ++j) {
        if (bkt[j] >= 0) {
            int s = startS[bkt[j]] + rnk[j];
            buf[s] = p[j];
            bk[s] = (unsigned short)bkt[j];
        }
    }
    __syncthreads();

    int total = startS[NB - 1] + cntS[NB - 1];
    for (int s = tid; s < total; s += TA_THREADS) {
        int b = bk[s];
        int dst = gbase[b] + (s - startS[b]);
        if (dst < (b + 1) * RCAP) binned[dst] = buf[s];   // overflow guard (never triggers)
    }
}

// -------------------- Pass B: per-bucket local CSR (count+scan+scatter in LDS) ----
// Emits cnt[row], offs[row] (offsets local to recsE / recsU per side) and the
// row-sorted record arrays. Row slot-runs are padded to even for 16B loads.
__global__ __launch_bounds__(512) void bucket_scatter_kernel(
    const unsigned long long* __restrict__ binned,
    const int* __restrict__ bcur,
    unsigned int* __restrict__ recsE,
    unsigned long long* __restrict__ recsU,
    int* __restrict__ cnt, int* __restrict__ offs)
{
    __shared__ int rowcnt[BROWS];
    __shared__ int sA[512], sB[512];

    int tid = threadIdx.x;
    int b = blockIdx.x;
    rowcnt[2 * tid] = 0;
    rowcnt[2 * tid + 1] = 0;
    __syncthreads();

    int s0 = b * RCAP;
    int s1 = bcur[b];
    if (s1 > s0 + RCAP) s1 = s0 + RCAP;

    // pass 1: per-row counts
    for (int i = s0 + tid; i < s1; i += 512) {
        int rowlo = (int)(binned[i] >> 50) & (BROWS - 1);
        atomicAdd(&rowcnt[rowlo], 1);
    }
    __syncthreads();

    int c0 = rowcnt[2 * tid];
    int c1 = rowcnt[2 * tid + 1];
    int pc0 = (c0 + 1) & ~1;               // pad to even
    int pc1 = (c1 + 1) & ~1;
    sA[tid] = pc0 + pc1;
    __syncthreads();
    int* src = sA; int* dst = sB;
    #pragma unroll
    for (int off = 1; off < 512; off <<= 1) {
        dst[tid] = src[tid] + ((tid >= off) ? src[tid - off] : 0);
        __syncthreads();
        int* tm = src; src = dst; dst = tm;
    }
    int excl = src[tid] - (pc0 + pc1);

    int gbaseOut = (b < EBUCKETS ? b : b - EBUCKETS) * RCAP_OUT;
    int grow = b * BROWS;
    cnt[grow + 2 * tid] = c0;
    offs[grow + 2 * tid] = gbaseOut + excl;
    cnt[grow + 2 * tid + 1] = c1;
    offs[grow + 2 * tid + 1] = gbaseOut + excl + pc0;
    __syncthreads();
    rowcnt[2 * tid] = excl;                 // repurpose as cursors (bucket-local)
    rowcnt[2 * tid + 1] = excl + pc0;
    __syncthreads();

    // pass 2: scatter to final slots
    if (b < EBUCKETS) {
        for (int i = s0 + tid; i < s1; i += 512) {
            unsigned long long p = binned[i];
            int rowlo = (int)(p >> 50) & (BROWS - 1);
            int local = atomicAdd(&rowcnt[rowlo], 1);
            recsE[gbaseOut + local] = (unsigned)(p & ((1ull << 50) - 1));
        }
    } else {
        for (int i = s0 + tid; i < s1; i += 512) {
            unsigned long long p = binned[i];
            int rowlo = (int)(p >> 50) & (BROWS - 1);
            int local = atomicAdd(&rowcnt[rowlo], 1);
            recsU[gbaseOut + local] = p & ((1ull << 50) - 1);
        }
    }
}

// -------------------- fused hop: 8 lanes per row, 8 bf16 (uint4) per lane ------------
__device__ __forceinline__ void fma8w(uint4 g, const float* __restrict__ w, float* acc) {
    acc[0] += __uint_as_float(g.x << 16)          * w[0];
    acc[1] += __uint_as_float(g.x & 0xffff0000u)  * w[1];
    acc[2] += __uint_as_float(g.y << 16)          * w[2];
    acc[3] += __uint_as_float(g.y & 0xffff0000u)  * w[3];
    acc[4] += __uint_as_float(g.z << 16)          * w[4];
    acc[5] += __uint_as_float(g.z & 0xffff0000u)  * w[5];
    acc[6] += __uint_as_float(g.w << 16)          * w[6];
    acc[7] += __uint_as_float(g.w & 0xffff0000u)  * w[7];
}
__device__ __forceinline__ void fma8v(uint4 g, float v, float* acc) {
    acc[0] += __uint_as_float(g.x << 16)          * v;
    acc[1] += __uint_as_float(g.x & 0xffff0000u)  * v;
    acc[2] += __uint_as_float(g.y << 16)          * v;
    acc[3] += __uint_as_float(g.y & 0xffff0000u)  * v;
    acc[4] += __uint_as_float(g.z << 16)          * v;
    acc[5] += __uint_as_float(g.z & 0xffff0000u)  * v;
    acc[6] += __uint_as_float(g.w << 16)          * v;
    acc[7] += __uint_as_float(g.w & 0xffff0000u)  * v;
}

__global__ __launch_bounds__(256) void hop_kernel(const unsigned short* __restrict__ ebf,  // [N_ENTITIES][64] bf16
                                                  const float* __restrict__ u_src,
                                                  const unsigned int* __restrict__ recsE,
                                                  const unsigned long long* __restrict__ recsU,
                                                  const int* __restrict__ cnt,
                                                  const int* __restrict__ offs,
                                                  const float* __restrict__ weight,  // [16][64] f32
                                                  const float* __restrict__ latent,  // [4][64]
                                                  const float* __restrict__ disenw,  // [4][64]
                                                  const float* __restrict__ ent_resid,
                                                  const float* __restrict__ usr_resid,
                                                  unsigned short* __restrict__ ebf_new,  // nullptr: skip
                                                  float* __restrict__ u_new,             // nullptr: skip
                                                  float* __restrict__ out_ent,
                                                  float* __restrict__ out_usr)
{
    __shared__ float wl[N_RELM1 * CHN];
    for (int k = threadIdx.x; k < N_RELM1 * CHN; k += 256) wl[k] = weight[k];
    __syncthreads();

    unsigned idx = blockIdx.x * 256u + threadIdx.x;
    unsigned row = idx >> 3;          // 8 lanes per row
    int sub = idx & 7;                // channels [sub*8, sub*8+8)
    int chb = sub * 8;

    float acc[8] = {0.f,0.f,0.f,0.f,0.f,0.f,0.f,0.f};

    if (row < N_ENTITIES) {
        int n = cnt[row];
        int start = offs[row];
        int k = 0;
        for (; k + 4 <= n; k += 4) {
            uint2 ra = *(const uint2*)&recsE[start + k];
            uint2 rb = *(const uint2*)&recsE[start + k + 2];
            uint4 g0 = *(const uint4*)(ebf + (size_t)(ra.x & 0x3FFFF) * CHN + chb);
            uint4 g1 = *(const uint4*)(ebf + (size_t)(ra.y & 0x3FFFF) * CHN + chb);
            uint4 g2 = *(const uint4*)(ebf + (size_t)(rb.x & 0x3FFFF) * CHN + chb);
            uint4 g3 = *(const uint4*)(ebf + (size_t)(rb.y & 0x3FFFF) * CHN + chb);
            fma8w(g0, &wl[(ra.x >> 18) * CHN + chb], acc);
            fma8w(g1, &wl[(ra.y >> 18) * CHN + chb], acc);
            fma8w(g2, &wl[(rb.x >> 18) * CHN + chb], acc);
            fma8w(g3, &wl[(rb.y >> 18) * CHN + chb], acc);
        }
        for (; k < n; ++k) {
            unsigned r0 = recsE[start + k];
            uint4 g0 = *(const uint4*)(ebf + (size_t)(r0 & 0x3FFFF) * CHN + chb);
            fma8w(g0, &wl[(r0 >> 18) * CHN + chb], acc);
        }
        float inv_d = (n > 0) ? (1.f / (float)n) : 1.f;
        float ss = 0.f;
        #pragma unroll
        for (int i = 0; i < 8; ++i) { acc[i] *= inv_d; ss += acc[i] * acc[i]; }
        ss += __shfl_xor(ss, 1, 64);
        ss += __shfl_xor(ss, 2, 64);
        ss += __shfl_xor(ss, 4, 64);
        float innv = 1.f / fmaxf(sqrtf(ss), 1e-12f);
        float y[8];
        #pragma unroll
        for (int i = 0; i < 8; ++i) y[i] = acc[i] * innv;
        if (ebf_new) {
            uint4 pk;
            pk.x = (unsigned)f2bf(y[0]) | ((unsigned)f2bf(y[1]) << 16);
            pk.y = (unsigned)f2bf(y[2]) | ((unsigned)f2bf(y[3]) << 16);
            pk.z = (unsigned)f2bf(y[4]) | ((unsigned)f2bf(y[5]) << 16);
            pk.w = (unsigned)f2bf(y[6]) | ((unsigned)f2bf(y[7]) << 16);
            *(uint4*)(ebf_new + (size_t)row * CHN + chb) = pk;
        }
        const vf4* rp = (const vf4*)&ent_resid[(size_t)row * CHN + chb];
        vf4 r0 = __builtin_nontemporal_load(rp);
        vf4 r1 = __builtin_nontemporal_load(rp + 1);
        vf4* op = (vf4*)&out_ent[(size_t)row * CHN + chb];
        vf4 o0 = {r0.x + y[0], r0.y + y[1], r0.z + y[2], r0.w + y[3]};
        vf4 o1 = {r1.x + y[4], r1.y + y[5], r1.z + y[6], r1.w + y[7]};
        __builtin_nontemporal_store(o0, op);
        __builtin_nontemporal_store(o1, op + 1);
    } else if (row >= USR0 && row < ROWS_EFF) {
        unsigned ur = row - USR0;
        int n = cnt[row];
        int start = offs[row];

        const float4* up = (const float4*)&u_src[(size_t)ur * CHN + chb];
        float4 uo0 = up[0], uo1 = up[1];

        float dotv[N_FACTORS];
        #pragma unroll
        for (int f = 0; f < N_FACTORS; ++f) {
            const float4* lp = (const float4*)&latent[f * CHN + chb];
            float4 l0 = lp[0], l1 = lp[1];
            float p = uo0.x * l0.x + uo0.y * l0.y + uo0.z * l0.z + uo0.w * l0.w
                    + uo1.x * l1.x + uo1.y * l1.y + uo1.z * l1.z + uo1.w * l1.w;
            p += __shfl_xor(p, 1, 64);
            p += __shfl_xor(p, 2, 64);
            p += __shfl_xor(p, 4, 64);
            dotv[f] = p;
        }
        float m = fmaxf(fmaxf(dotv[0], dotv[1]), fmaxf(dotv[2], dotv[3]));
        float es = 0.f;
        #pragma unroll
        for (int f = 0; f < N_FACTORS; ++f) { dotv[f] = expf(dotv[f] - m); es += dotv[f]; }
        float sinv = 1.f / es;
        float mix[8] = {0.f,0.f,0.f,0.f,0.f,0.f,0.f,0.f};
        #pragma unroll
        for (int f = 0; f < N_FACTORS; ++f) {
            float sc = dotv[f] * sinv;
            const float4* dp = (const float4*)&disenw[f * CHN + chb];
            float4 d0 = dp[0], d1 = dp[1];
            mix[0] += sc * d0.x; mix[1] += sc * d0.y; mix[2] += sc * d0.z; mix[3] += sc * d0.w;
            mix[4] += sc * d1.x; mix[5] += sc * d1.y; mix[6] += sc * d1.z; mix[7] += sc * d1.w;
        }

        int k = 0;
        for (; k + 4 <= n; k += 4) {
            ulonglong2 qa = *(const ulonglong2*)&recsU[start + k];
            ulonglong2 qb = *(const ulonglong2*)&recsU[start + k + 2];
            uint4 g0 = *(const uint4*)(ebf + (size_t)(qa.x & 0x3FFFFu) * CHN + chb);
            uint4 g1 = *(const uint4*)(ebf + (size_t)(qa.y & 0x3FFFFu) * CHN + chb);
            uint4 g2 = *(const uint4*)(ebf + (size_t)(qb.x & 0x3FFFFu) * CHN + chb);
            uint4 g3 = *(const uint4*)(ebf + (size_t)(qb.y & 0x3FFFFu) * CHN + chb);
            fma8v(g0, __uint_as_float((unsigned)(qa.x >> 18)), acc);
            fma8v(g1, __uint_as_float((unsigned)(qa.y >> 18)), acc);
            fma8v(g2, __uint_as_float((unsigned)(qb.x >> 18)), acc);
            fma8v(g3, __uint_as_float((unsigned)(qb.y >> 18)), acc);
        }
        for (; k < n; ++k) {
            unsigned long long q0 = recsU[start + k];
            uint4 g0 = *(const uint4*)(ebf + (size_t)(q0 & 0x3FFFFu) * CHN + chb);
            fma8v(g0, __uint_as_float((unsigned)(q0 >> 18)), acc);
        }
        float ss = 0.f;
        #pragma unroll
        for (int i = 0; i < 8; ++i) { acc[i] *= (1.f + mix[i]); ss += acc[i] * acc[i]; }
        ss += __shfl_xor(ss, 1, 64);
        ss += __shfl_xor(ss, 2, 64);
        ss += __shfl_xor(ss, 4, 64);
        float innv = 1.f / fmaxf(sqrtf(ss), 1e-12f);
        float y[8];
        #pragma unroll
        for (int i = 0; i < 8; ++i) y[i] = acc[i] * innv;
        if (u_new) {
            float4* np = (float4*)&u_new[(size_t)ur * CHN + chb];
            np[0] = make_float4(y[0], y[1], y[2], y[3]);
            np[1] = make_float4(y[4], y[5], y[6], y[7]);
        }
        const vf4* rp = (const vf4*)&usr_resid[(size_t)ur * CHN + chb];
        vf4 r0 = __builtin_nontemporal_load(rp);
        vf4 r1 = __builtin_nontemporal_load(rp + 1);
        vf4* op = (vf4*)&out_usr[(size_t)ur * CHN + chb];
        vf4 o0 = {r0.x + y[0], r0.y + y[1], r0.z + y[2], r0.w + y[3]};
        vf4 o1 = {r1.x + y[4], r1.y + y[5], r1.z + y[6], r1.w + y[7]};
        __builtin_nontemporal_store(o0, op);
        __builtin_nontemporal_store(o1, op + 1);
    }
}

extern "C" void kernel_launch(void* const* d_in, const int* in_sizes, int n_in,
                              void* d_out, int out_size, void* d_ws, size_t ws_size,
                              hipStream_t stream) {
    const float* user_emb   = (const float*)d_in[0];
    const float* entity_emb = (const float*)d_in[1];
    const float* latent_emb = (const float*)d_in[2];
    const float* weight     = (const float*)d_in[3];
    const float* att        = (const float*)d_in[4];
    const float* inter_val  = (const float*)d_in[5];
    const int*   edge_index = (const int*)d_in[6];   // [2][N_EDGES]
    const int*   edge_type  = (const int*)d_in[7];
    const int*   inter_row  = (const int*)d_in[8];
    const int*   inter_col  = (const int*)d_in[9];

    const int* head = edge_index;
    const int* tail = edge_index + N_EDGES;

    float* out_ent = (float*)d_out;                              // [250000*64]
    float* out_usr = out_ent + (size_t)N_ENTITIES * CHN;         // [150000*64]
    float* out_cor = out_usr + (size_t)N_USERS * CHN;            // [1]

    // workspace layout (byte offsets kept 16B-aligned)
    char* ws = (char*)d_ws;
    unsigned short* ebf0   = (unsigned short*)ws;                             // 32,000,000 B
    unsigned short* ebfA   = (unsigned short*)(ws + 32000000);                // 32,000,000 B
    unsigned long long* binned = (unsigned long long*)(ws + 64000000);        // NB*RCAP u64 = 25,690,112 B
    unsigned long long* recsU  = (unsigned long long*)(ws + 89690112);        // 147*RCAP_OUT u64 = 9,633,792 B
    unsigned int* recsE    = (unsigned int*)(ws + 99323904);                  // 245*RCAP_OUT u32 = 8,028,160 B
    float* u               = (float*)(ws + 107352064);                        // 38,400,000 B
    float* disenw          = (float*)(ws + 145752064);                        // 1,024 B
    int*   cnt             = (int*)(ws + 145753088);                          // NB*BROWS i = 1,605,632 B
    int*   offs            = (int*)(ws + 147358720);                          // 1,605,632 B
    int*   bcur            = (int*)(ws + 148964352);                          // NB i

    // ---- prep (disenw, cor, bucket cursors) ----
    prep_small_kernel<<<1, 512, 0, stream>>>(weight, att, disenw, out_cor, bcur);

    // ---- bf16 copy of input entity table ----
    {
        int n4 = N_ENTITIES * CHN / 4;                           // 4,000,000
        conv_bf16_kernel<<<(n4 + 255) / 256, 256, 0, stream>>>(
            (const float4*)entity_emb, (ushort4*)ebf0, n4);
    }

    // ---- two-pass scatter with fused local CSR ----
    const int binA_blocks = (NRECS + TILE_A - 1) / TILE_A;       // 489
    bin_pass_kernel<<<binA_blocks, TA_THREADS, 0, stream>>>(head, tail, edge_type,
                                                            inter_row, inter_col, inter_val,
                                                            bcur, binned);
    bucket_scatter_kernel<<<NB, 512, 0, stream>>>(binned, bcur, recsE, recsU, cnt, offs);

    const int hop_blocks = (ROWS_EFF * 8 + 255) / 256;           // 12528

    // ---- hop 1: gather from ebf0; residual base = inputs; emit ebfA + u ----
    hop_kernel<<<hop_blocks, 256, 0, stream>>>(ebf0, user_emb, recsE, recsU,
                                               cnt, offs, weight, latent_emb, disenw,
                                               entity_emb, user_emb,
                                               ebfA, u, out_ent, out_usr);

    // ---- hop 2: gather from ebfA; residual base = out (in-place add) ----
    hop_kernel<<<hop_blocks, 256, 0, stream>>>(ebfA, u, recsE, recsU,
                                               cnt, offs, weight, latent_emb, disenw,
                                               out_ent, out_usr,
                                               nullptr, nullptr, out_ent, out_usr);
}

// Round 9
// 227.113 us; speedup vs baseline: 2.2390x; 1.1298x over previous
//
#include <hip/hip_runtime.h>
#include <hip/hip_bf16.h>

// Problem constants (from reference)
#define N_USERS    150000
#define N_ENTITIES 250000
#define CHN        64
#define N_RELM1    16
#define N_FACTORS  4
#define N_EDGES    1000000
#define NNZ_       1000000
#define NRECS      (N_EDGES + NNZ_)

// fixed-capacity bucket decomposition (row-space: entities [0,250000), users [USR0, USR0+150000))
#define BROWS      1024
#define RCAP       8192                       // binned-region capacity per bucket (u64 records)
#define RCAP_OUT   8192                       // output recsE/recsU region capacity per bucket
#define EBUCKETS   245                        // ceil(250000/1024)
#define USR0       (EBUCKETS * BROWS)         // 250880
#define ROWS_EFF   (USR0 + N_USERS)           // 400880
#define NB         392                        // ceil(ROWS_EFF/1024)
#define TILE_A     4096
#define TA_THREADS 512
#define ITEMS_A    8

typedef float vf4 __attribute__((ext_vector_type(4)));   // Clang vector: ok for nontemporal builtins

__device__ __forceinline__ unsigned short f2bf(float f) {
    unsigned u = __float_as_uint(f);
    return (unsigned short)((u + 0x7fffu + ((u >> 16) & 1u)) >> 16);  // RNE
}

// -------------------- prep: disen_weight + cor + bucket cursor init --------------------
__global__ __launch_bounds__(512) void prep_small_kernel(const float* __restrict__ weight,   // [16][64]
                                  const float* __restrict__ att,      // [4][16]
                                  float* __restrict__ disenw,         // [4][64] out
                                  float* __restrict__ cor_out,        // scalar out
                                  int* __restrict__ bcur)
{
    int tid = threadIdx.x;
    if (tid < NB) bcur[tid] = tid * RCAP;

    if (tid < 256) {
        int f  = tid >> 6;
        int ch = tid & 63;
        float m = -1e30f;
        for (int r = 0; r < N_RELM1; ++r) m = fmaxf(m, att[f * N_RELM1 + r]);
        float ex[N_RELM1];
        float s = 0.f;
        for (int r = 0; r < N_RELM1; ++r) { ex[r] = expf(att[f * N_RELM1 + r] - m); s += ex[r]; }
        float inv = 1.f / s;
        float acc = 0.f;
        for (int r = 0; r < N_RELM1; ++r) acc += (ex[r] * inv) * weight[r * CHN + ch];
        disenw[f * CHN + ch] = acc;
    }

    if (tid == 0) {
        float wn[N_FACTORS][N_RELM1];
        for (int i = 0; i < N_FACTORS; ++i) {
            float ss = 0.f;
            for (int r = 0; r < N_RELM1; ++r) { float v = att[i * N_RELM1 + r]; ss += v * v; }
            float innv = 1.f / sqrtf(ss);
            for (int r = 0; r < N_RELM1; ++r) wn[i][r] = att[i * N_RELM1 + r] * innv;
        }
        float cor = 0.f;
        for (int i = 0; i < N_FACTORS; ++i)
            for (int j = i + 1; j < N_FACTORS; ++j) {
                float d = 0.f;
                for (int r = 0; r < N_RELM1; ++r) d += wn[i][r] * wn[j][r];
                cor += d * d;
            }
        cor_out[0] = cor;
    }
}

// -------------------- f32 -> bf16 table conversion --------------------
__global__ __launch_bounds__(256) void conv_bf16_kernel(const float4* __restrict__ src,
                                                        ushort4* __restrict__ dst, int n4)
{
    int i = blockIdx.x * 256 + threadIdx.x;
    if (i >= n4) return;
    float4 v = src[i];
    dst[i] = make_ushort4(f2bf(v.x), f2bf(v.y), f2bf(v.z), f2bf(v.w));
}

// -------------------- Pass A: LDS-staged binning into fixed-capacity buckets ----
// Record u64: rowlo(10b)<<50 | payload(50b).
//   entity payload: (rel 4b)<<18 | tail 18b
//   user payload:   (val f32)<<18 | col 18b
__global__ __launch_bounds__(TA_THREADS) void bin_pass_kernel(
    const int* __restrict__ head, const int* __restrict__ tail,
    const int* __restrict__ etype, const int* __restrict__ irow,
    const int* __restrict__ icol, const float* __restrict__ val,
    int* __restrict__ bcur, unsigned long long* __restrict__ binned)
{
    __shared__ int cntS[NB], startS[NB], gbase[NB];
    __shared__ unsigned long long buf[TILE_A];
    __shared__ unsigned short bk[TILE_A];

    int tid = threadIdx.x;
    if (tid < NB) cntS[tid] = 0;
    __syncthreads();

    int base = blockIdx.x * TILE_A;
    unsigned long long p[ITEMS_A];
    int bkt[ITEMS_A], rnk[ITEMS_A];
    #pragma unroll
    for (int j = 0; j < ITEMS_A; ++j) {
        int i = base + j * TA_THREADS + tid;
        bkt[j] = -1;
        if (i < NRECS) {
            int row; unsigned long long pay;
            if (i < N_EDGES) {
                row = head[i];
                pay = ((unsigned long long)(unsigned)(etype[i] - 1) << 18) | (unsigned)tail[i];
            } else {
                int jj = i - N_EDGES;
                row = USR0 + irow[jj];
                pay = ((unsigned long long)__float_as_uint(val[jj]) << 18) | (unsigned)icol[jj];
            }
            p[j] = pay | ((unsigned long long)(unsigned)(row & (BROWS - 1)) << 50);
            bkt[j] = row >> 10;
            rnk[j] = atomicAdd(&cntS[bkt[j]], 1);
        }
    }
    __syncthreads();
    if (tid == 0) {
        int s = 0;
        for (int b = 0; b < NB; ++b) { startS[b] = s; s += cntS[b]; }
    }
    __syncthreads();
    if (tid < NB && cntS[tid] > 0) gbase[tid] = atomicAdd(&bcur[tid], cntS[tid]);
    __syncthreads();

    #pragma unroll
    for (int j = 0; j < ITEMS_A; ++j) {
        if (bkt[j] >= 0) {
            int s = startS[bkt[j]] + rnk[j];
            buf[s] = p[j];
            bk[s] = (unsigned short)bkt[j];
        }
    }
    __syncthreads();

    int total = startS[NB - 1] + cntS[NB - 1];
    for (int s = tid; s < total; s += TA_THREADS) {
        int b = bk[s];
        int dst = gbase[b] + (s - startS[b]);
        if (dst < (b + 1) * RCAP) binned[dst] = buf[s];   // overflow guard (never triggers)
    }
}

// -------------------- Pass B: per-bucket local CSR; emits packed (cnt<<22|offs) ----
__global__ __launch_bounds__(512) void bucket_scatter_kernel(
    const unsigned long long* __restrict__ binned,
    const int* __restrict__ bcur,
    unsigned int* __restrict__ recsE,
    unsigned long long* __restrict__ recsU,
    unsigned int* __restrict__ cntoffs)
{
    __shared__ int rowcnt[BROWS];
    __shared__ int sA[512], sB[512];

    int tid = threadIdx.x;
    int b = blockIdx.x;
    rowcnt[2 * tid] = 0;
    rowcnt[2 * tid + 1] = 0;
    __syncthreads();

    int s0 = b * RCAP;
    int s1 = bcur[b];
    if (s1 > s0 + RCAP) s1 = s0 + RCAP;

    // pass 1: per-row counts
    for (int i = s0 + tid; i < s1; i += 512) {
        int rowlo = (int)(binned[i] >> 50) & (BROWS - 1);
        atomicAdd(&rowcnt[rowlo], 1);
    }
    __syncthreads();

    int c0 = rowcnt[2 * tid];
    int c1 = rowcnt[2 * tid + 1];
    int pc0 = (c0 + 1) & ~1;               // pad to even
    int pc1 = (c1 + 1) & ~1;
    sA[tid] = pc0 + pc1;
    __syncthreads();
    int* src = sA; int* dst = sB;
    #pragma unroll
    for (int off = 1; off < 512; off <<= 1) {
        dst[tid] = src[tid] + ((tid >= off) ? src[tid - off] : 0);
        __syncthreads();
        int* tm = src; src = dst; dst = tm;
    }
    int excl = src[tid] - (pc0 + pc1);

    int gbaseOut = (b < EBUCKETS ? b : b - EBUCKETS) * RCAP_OUT;
    int grow = b * BROWS;
    cntoffs[grow + 2 * tid]     = ((unsigned)c0 << 22) | (unsigned)(gbaseOut + excl);
    cntoffs[grow + 2 * tid + 1] = ((unsigned)c1 << 22) | (unsigned)(gbaseOut + excl + pc0);
    __syncthreads();
    rowcnt[2 * tid] = excl;                 // repurpose as cursors (bucket-local)
    rowcnt[2 * tid + 1] = excl + pc0;
    __syncthreads();

    // pass 2: scatter to final slots
    if (b < EBUCKETS) {
        for (int i = s0 + tid; i < s1; i += 512) {
            unsigned long long p = binned[i];
            int rowlo = (int)(p >> 50) & (BROWS - 1);
            int local = atomicAdd(&rowcnt[rowlo], 1);
            recsE[gbaseOut + local] = (unsigned)(p & ((1ull << 50) - 1));
        }
    } else {
        for (int i = s0 + tid; i < s1; i += 512) {
            unsigned long long p = binned[i];
            int rowlo = (int)(p >> 50) & (BROWS - 1);
            int local = atomicAdd(&rowcnt[rowlo], 1);
            recsU[gbaseOut + local] = p & ((1ull << 50) - 1);
        }
    }
}

// -------------------- fused hop: 8 lanes per row, 8 bf16 (uint4) per lane ------------
__device__ __forceinline__ void fma8w(uint4 g, const float* __restrict__ w, float* acc) {
    acc[0] += __uint_as_float(g.x << 16)          * w[0];
    acc[1] += __uint_as_float(g.x & 0xffff0000u)  * w[1];
    acc[2] += __uint_as_float(g.y << 16)          * w[2];
    acc[3] += __uint_as_float(g.y & 0xffff0000u)  * w[3];
    acc[4] += __uint_as_float(g.z << 16)          * w[4];
    acc[5] += __uint_as_float(g.z & 0xffff0000u)  * w[5];
    acc[6] += __uint_as_float(g.w << 16)          * w[6];
    acc[7] += __uint_as_float(g.w & 0xffff0000u)  * w[7];
}
__device__ __forceinline__ void fma8v(uint4 g, float v, float* acc) {
    acc[0] += __uint_as_float(g.x << 16)          * v;
    acc[1] += __uint_as_float(g.x & 0xffff0000u)  * v;
    acc[2] += __uint_as_float(g.y << 16)          * v;
    acc[3] += __uint_as_float(g.y & 0xffff0000u)  * v;
    acc[4] += __uint_as_float(g.z << 16)          * v;
    acc[5] += __uint_as_float(g.z & 0xffff0000u)  * v;
    acc[6] += __uint_as_float(g.w << 16)          * v;
    acc[7] += __uint_as_float(g.w & 0xffff0000u)  * v;
}
__device__ __forceinline__ void bf8_unpack(uint4 g, float* o) {
    o[0] = __uint_as_float(g.x << 16); o[1] = __uint_as_float(g.x & 0xffff0000u);
    o[2] = __uint_as_float(g.y << 16); o[3] = __uint_as_float(g.y & 0xffff0000u);
    o[4] = __uint_as_float(g.z << 16); o[5] = __uint_as_float(g.z & 0xffff0000u);
    o[6] = __uint_as_float(g.w << 16); o[7] = __uint_as_float(g.w & 0xffff0000u);
}

// PASS 1: gather from ebf0 -> write compact bf16 state only (ebfA, ubfA).
// PASS 2: gather from ebfA -> out = emb(f32) + y1(bf16, own-row) + y2.
template<int PASS>
__global__ __launch_bounds__(256) void hop_kernel(
    const unsigned short* __restrict__ ebf,     // gather table (pass1: ebf0, pass2: ebfA)
    const unsigned int* __restrict__ recsE,
    const unsigned long long* __restrict__ recsU,
    const unsigned int* __restrict__ cntoffs,
    const float* __restrict__ weight,           // [16][64] f32
    const float* __restrict__ latent,           // [4][64]
    const float* __restrict__ disenw,           // [4][64]
    const float* __restrict__ u_emb,            // user_emb f32 (pass1: softmax src; pass2: base)
    const float* __restrict__ e_emb,            // entity_emb f32 (pass2 base)
    const unsigned short* __restrict__ ubfA,    // pass2: u1 bf16 (softmax src + residual term)
    unsigned short* __restrict__ ebf_new,       // pass1 out
    unsigned short* __restrict__ ubf_new,       // pass1 out
    float* __restrict__ out_ent,                // pass2 out
    float* __restrict__ out_usr)                // pass2 out
{
    __shared__ float wl[N_RELM1 * CHN];
    for (int k = threadIdx.x; k < N_RELM1 * CHN; k += 256) wl[k] = weight[k];
    __syncthreads();

    unsigned idx = blockIdx.x * 256u + threadIdx.x;
    unsigned row = idx >> 3;          // 8 lanes per row
    int sub = idx & 7;                // channels [sub*8, sub*8+8)
    int chb = sub * 8;

    float acc[8] = {0.f,0.f,0.f,0.f,0.f,0.f,0.f,0.f};

    if (row < N_ENTITIES) {
        unsigned co = cntoffs[row];
        int n = co >> 22;
        int start = co & 0x3FFFFF;
        int k = 0;
        for (; k + 4 <= n; k += 4) {
            uint2 ra = *(const uint2*)&recsE[start + k];
            uint2 rb = *(const uint2*)&recsE[start + k + 2];
            uint4 g0 = *(const uint4*)(ebf + (size_t)(ra.x & 0x3FFFF) * CHN + chb);
            uint4 g1 = *(const uint4*)(ebf + (size_t)(ra.y & 0x3FFFF) * CHN + chb);
            uint4 g2 = *(const uint4*)(ebf + (size_t)(rb.x & 0x3FFFF) * CHN + chb);
            uint4 g3 = *(const uint4*)(ebf + (size_t)(rb.y & 0x3FFFF) * CHN + chb);
            fma8w(g0, &wl[(ra.x >> 18) * CHN + chb], acc);
            fma8w(g1, &wl[(ra.y >> 18) * CHN + chb], acc);
            fma8w(g2, &wl[(rb.x >> 18) * CHN + chb], acc);
            fma8w(g3, &wl[(rb.y >> 18) * CHN + chb], acc);
        }
        for (; k < n; ++k) {
            unsigned r0 = recsE[start + k];
            uint4 g0 = *(const uint4*)(ebf + (size_t)(r0 & 0x3FFFF) * CHN + chb);
            fma8w(g0, &wl[(r0 >> 18) * CHN + chb], acc);
        }
        float inv_d = (n > 0) ? (1.f / (float)n) : 1.f;
        float ss = 0.f;
        #pragma unroll
        for (int i = 0; i < 8; ++i) { acc[i] *= inv_d; ss += acc[i] * acc[i]; }
        ss += __shfl_xor(ss, 1, 64);
        ss += __shfl_xor(ss, 2, 64);
        ss += __shfl_xor(ss, 4, 64);
        float innv = 1.f / fmaxf(sqrtf(ss), 1e-12f);
        float y[8];
        #pragma unroll
        for (int i = 0; i < 8; ++i) y[i] = acc[i] * innv;
        if (PASS == 1) {
            uint4 pk;
            pk.x = (unsigned)f2bf(y[0]) | ((unsigned)f2bf(y[1]) << 16);
            pk.y = (unsigned)f2bf(y[2]) | ((unsigned)f2bf(y[3]) << 16);
            pk.z = (unsigned)f2bf(y[4]) | ((unsigned)f2bf(y[5]) << 16);
            pk.w = (unsigned)f2bf(y[6]) | ((unsigned)f2bf(y[7]) << 16);
            *(uint4*)(ebf_new + (size_t)row * CHN + chb) = pk;
        } else {
            float y1[8];
            bf8_unpack(*(const uint4*)(ebf + (size_t)row * CHN + chb), y1);  // own hop-1 value
            const vf4* bp = (const vf4*)&e_emb[(size_t)row * CHN + chb];
            vf4 b0 = __builtin_nontemporal_load(bp);
            vf4 b1 = __builtin_nontemporal_load(bp + 1);
            vf4* op = (vf4*)&out_ent[(size_t)row * CHN + chb];
            vf4 o0 = {b0.x + y1[0] + y[0], b0.y + y1[1] + y[1], b0.z + y1[2] + y[2], b0.w + y1[3] + y[3]};
            vf4 o1 = {b1.x + y1[4] + y[4], b1.y + y1[5] + y[5], b1.z + y1[6] + y[6], b1.w + y1[7] + y[7]};
            __builtin_nontemporal_store(o0, op);
            __builtin_nontemporal_store(o1, op + 1);
        }
    } else if (row >= USR0 && row < ROWS_EFF) {
        unsigned ur = row - USR0;
        unsigned co = cntoffs[row];
        int n = co >> 22;
        int start = co & 0x3FFFFF;

        float uo[8];
        if (PASS == 1) {
            const float4* up = (const float4*)&u_emb[(size_t)ur * CHN + chb];
            float4 a0 = up[0], a1 = up[1];
            uo[0]=a0.x; uo[1]=a0.y; uo[2]=a0.z; uo[3]=a0.w;
            uo[4]=a1.x; uo[5]=a1.y; uo[6]=a1.z; uo[7]=a1.w;
        } else {
            bf8_unpack(*(const uint4*)(ubfA + (size_t)ur * CHN + chb), uo);
        }

        float dotv[N_FACTORS];
        #pragma unroll
        for (int f = 0; f < N_FACTORS; ++f) {
            const float4* lp = (const float4*)&latent[f * CHN + chb];
            float4 l0 = lp[0], l1 = lp[1];
            float p = uo[0] * l0.x + uo[1] * l0.y + uo[2] * l0.z + uo[3] * l0.w
                    + uo[4] * l1.x + uo[5] * l1.y + uo[6] * l1.z + uo[7] * l1.w;
            p += __shfl_xor(p, 1, 64);
            p += __shfl_xor(p, 2, 64);
            p += __shfl_xor(p, 4, 64);
            dotv[f] = p;
        }
        float m = fmaxf(fmaxf(dotv[0], dotv[1]), fmaxf(dotv[2], dotv[3]));
        float es = 0.f;
        #pragma unroll
        for (int f = 0; f < N_FACTORS; ++f) { dotv[f] = expf(dotv[f] - m); es += dotv[f]; }
        float sinv = 1.f / es;
        float mix[8] = {0.f,0.f,0.f,0.f,0.f,0.f,0.f,0.f};
        #pragma unroll
        for (int f = 0; f < N_FACTORS; ++f) {
            float sc = dotv[f] * sinv;
            const float4* dp = (const float4*)&disenw[f * CHN + chb];
            float4 d0 = dp[0], d1 = dp[1];
            mix[0] += sc * d0.x; mix[1] += sc * d0.y; mix[2] += sc * d0.z; mix[3] += sc * d0.w;
            mix[4] += sc * d1.x; mix[5] += sc * d1.y; mix[6] += sc * d1.z; mix[7] += sc * d1.w;
        }

        int k = 0;
        for (; k + 4 <= n; k += 4) {
            ulonglong2 qa = *(const ulonglong2*)&recsU[start + k];
            ulonglong2 qb = *(const ulonglong2*)&recsU[start + k + 2];
            uint4 g0 = *(const uint4*)(ebf + (size_t)(qa.x & 0x3FFFFu) * CHN + chb);
            uint4 g1 = *(const uint4*)(ebf + (size_t)(qa.y & 0x3FFFFu) * CHN + chb);
            uint4 g2 = *(const uint4*)(ebf + (size_t)(qb.x & 0x3FFFFu) * CHN + chb);
            uint4 g3 = *(const uint4*)(ebf + (size_t)(qb.y & 0x3FFFFu) * CHN + chb);
            fma8v(g0, __uint_as_float((unsigned)(qa.x >> 18)), acc);
            fma8v(g1, __uint_as_float((unsigned)(qa.y >> 18)), acc);
            fma8v(g2, __uint_as_float((unsigned)(qb.x >> 18)), acc);
            fma8v(g3, __uint_as_float((unsigned)(qb.y >> 18)), acc);
        }
        for (; k < n; ++k) {
            unsigned long long q0 = recsU[start + k];
            uint4 g0 = *(const uint4*)(ebf + (size_t)(q0 & 0x3FFFFu) * CHN + chb);
            fma8v(g0, __uint_as_float((unsigned)(q0 >> 18)), acc);
        }
        float ss = 0.f;
        #pragma unroll
        for (int i = 0; i < 8; ++i) { acc[i] *= (1.f + mix[i]); ss += acc[i] * acc[i]; }
        ss += __shfl_xor(ss, 1, 64);
        ss += __shfl_xor(ss, 2, 64);
        ss += __shfl_xor(ss, 4, 64);
        float innv = 1.f / fmaxf(sqrtf(ss), 1e-12f);
        float y[8];
        #pragma unroll
        for (int i = 0; i < 8; ++i) y[i] = acc[i] * innv;
        if (PASS == 1) {
            uint4 pk;
            pk.x = (unsigned)f2bf(y[0]) | ((unsigned)f2bf(y[1]) << 16);
            pk.y = (unsigned)f2bf(y[2]) | ((unsigned)f2bf(y[3]) << 16);
            pk.z = (unsigned)f2bf(y[4]) | ((unsigned)f2bf(y[5]) << 16);
            pk.w = (unsigned)f2bf(y[6]) | ((unsigned)f2bf(y[7]) << 16);
            *(uint4*)(ubf_new + (size_t)ur * CHN + chb) = pk;
        } else {
            const vf4* bp = (const vf4*)&u_emb[(size_t)ur * CHN + chb];
            vf4 b0 = __builtin_nontemporal_load(bp);
            vf4 b1 = __builtin_nontemporal_load(bp + 1);
            vf4* op = (vf4*)&out_usr[(size_t)ur * CHN + chb];
            vf4 o0 = {b0.x + uo[0] + y[0], b0.y + uo[1] + y[1], b0.z + uo[2] + y[2], b0.w + uo[3] + y[3]};
            vf4 o1 = {b1.x + uo[4] + y[4], b1.y + uo[5] + y[5], b1.z + uo[6] + y[6], b1.w + uo[7] + y[7]};
            __builtin_nontemporal_store(o0, op);
            __builtin_nontemporal_store(o1, op + 1);
        }
    }
}

extern "C" void kernel_launch(void* const* d_in, const int* in_sizes, int n_in,
                              void* d_out, int out_size, void* d_ws, size_t ws_size,
                              hipStream_t stream) {
    const float* user_emb   = (const float*)d_in[0];
    const float* entity_emb = (const float*)d_in[1];
    const float* latent_emb = (const float*)d_in[2];
    const float* weight     = (const float*)d_in[3];
    const float* att        = (const float*)d_in[4];
    const float* inter_val  = (const float*)d_in[5];
    const int*   edge_index = (const int*)d_in[6];   // [2][N_EDGES]
    const int*   edge_type  = (const int*)d_in[7];
    const int*   inter_row  = (const int*)d_in[8];
    const int*   inter_col  = (const int*)d_in[9];

    const int* head = edge_index;
    const int* tail = edge_index + N_EDGES;

    float* out_ent = (float*)d_out;                              // [250000*64]
    float* out_usr = out_ent + (size_t)N_ENTITIES * CHN;         // [150000*64]
    float* out_cor = out_usr + (size_t)N_USERS * CHN;            // [1]

    // workspace layout (byte offsets kept 16B-aligned)
    char* ws = (char*)d_ws;
    unsigned short* ebf0   = (unsigned short*)ws;                             // 32,000,000 B
    unsigned short* ebfA   = (unsigned short*)(ws + 32000000);                // 32,000,000 B
    unsigned short* ubfA   = (unsigned short*)(ws + 64000000);                // 19,200,000 B
    unsigned long long* binned = (unsigned long long*)(ws + 83200000);        // NB*RCAP u64 = 25,690,112 B
    unsigned long long* recsU  = (unsigned long long*)(ws + 108890112);       // 147*RCAP_OUT u64 = 9,633,792 B
    unsigned int* recsE    = (unsigned int*)(ws + 118523904);                 // 245*RCAP_OUT u32 = 8,028,160 B
    float* disenw          = (float*)(ws + 126552064);                        // 1,024 B
    unsigned int* cntoffs  = (unsigned int*)(ws + 126553088);                 // NB*BROWS u32 = 1,605,632 B
    int*   bcur            = (int*)(ws + 128158720);                          // NB i

    // ---- prep (disenw, cor, bucket cursors) ----
    prep_small_kernel<<<1, 512, 0, stream>>>(weight, att, disenw, out_cor, bcur);

    // ---- bf16 copy of input entity table ----
    {
        int n4 = N_ENTITIES * CHN / 4;                           // 4,000,000
        conv_bf16_kernel<<<(n4 + 255) / 256, 256, 0, stream>>>(
            (const float4*)entity_emb, (ushort4*)ebf0, n4);
    }

    // ---- two-pass scatter with fused local CSR ----
    const int binA_blocks = (NRECS + TILE_A - 1) / TILE_A;       // 489
    bin_pass_kernel<<<binA_blocks, TA_THREADS, 0, stream>>>(head, tail, edge_type,
                                                            inter_row, inter_col, inter_val,
                                                            bcur, binned);
    bucket_scatter_kernel<<<NB, 512, 0, stream>>>(binned, bcur, recsE, recsU, cntoffs);

    const int hop_blocks = (ROWS_EFF * 8 + 255) / 256;           // 12528

    // ---- hop 1: gather from ebf0 -> compact bf16 state (ebfA, ubfA) ----
    hop_kernel<1><<<hop_blocks, 256, 0, stream>>>(ebf0, recsE, recsU, cntoffs,
                                                  weight, latent_emb, disenw,
                                                  user_emb, entity_emb, nullptr,
                                                  ebfA, ubfA, nullptr, nullptr);

    // ---- hop 2: gather from ebfA -> out = emb + y1 + y2 ----
    hop_kernel<2><<<hop_blocks, 256, 0, stream>>>(ebfA, recsE, recsU, cntoffs,
                                                  weight, latent_emb, disenw,
                                                  user_emb, entity_emb, ubfA,
                                                  nullptr, nullptr, out_ent, out_usr);
}

// Round 10
// 223.494 us; speedup vs baseline: 2.2753x; 1.0162x over previous
//
#include <hip/hip_runtime.h>
#include <hip/hip_bf16.h>

// Problem constants (from reference)
#define N_USERS    150000
#define N_ENTITIES 250000
#define CHN        64
#define N_RELM1    16
#define N_FACTORS  4
#define N_EDGES    1000000
#define NNZ_       1000000
#define NRECS      (N_EDGES + NNZ_)

// fixed-capacity bucket decomposition (row-space: entities [0,250000), users [USR0, USR0+150000))
#define BROWS      1024
#define RCAP       8192                       // binned-region capacity per bucket (u64 records)
#define RCAP_OUT   8192                       // output recsE/recsU region capacity per bucket
#define EBUCKETS   245                        // ceil(250000/1024)
#define USR0       (EBUCKETS * BROWS)         // 250880
#define ROWS_EFF   (USR0 + N_USERS)           // 400880
#define NB         392                        // ceil(ROWS_EFF/1024)
#define TILE_A     4096
#define TA_THREADS 512
#define ITEMS_A    8
#define BIN_BLOCKS 489                        // ceil(NRECS / TILE_A)
#define CONV_N4    (N_ENTITIES * CHN / 4)     // 4,000,000 float4 groups
#define CONV_BLOCKS ((CONV_N4 + 511) / 512)   // 7813

typedef float vf4 __attribute__((ext_vector_type(4)));   // Clang vector: ok for nontemporal builtins

__device__ __forceinline__ unsigned short f2bf(float f) {
    unsigned u = __float_as_uint(f);
    return (unsigned short)((u + 0x7fffu + ((u >> 16) & 1u)) >> 16);  // RNE
}

// -------------------- fused build: bin_pass + prep + bf16 conv --------------------
// Record u64: rowlo(10b)<<50 | payload(50b).
//   entity payload: (rel 4b)<<18 | tail 18b
//   user payload:   (val f32)<<18 | col 18b
__global__ __launch_bounds__(512) void build_kernel(
    const int* __restrict__ head, const int* __restrict__ tail,
    const int* __restrict__ etype, const int* __restrict__ irow,
    const int* __restrict__ icol, const float* __restrict__ val,
    int* __restrict__ bcur, unsigned long long* __restrict__ binned,
    const float* __restrict__ weight, const float* __restrict__ att,
    float* __restrict__ disenw, float* __restrict__ cor_out,
    const float4* __restrict__ esrc, ushort4* __restrict__ ebf0)
{
    int blk = blockIdx.x;
    int tid = threadIdx.x;

    if (blk < BIN_BLOCKS) {
        __shared__ int cntS[NB], startS[NB], gbase[NB];
        __shared__ unsigned long long buf[TILE_A];
        __shared__ unsigned short bk[TILE_A];

        if (tid < NB) cntS[tid] = 0;
        __syncthreads();

        int base = blk * TILE_A;
        unsigned long long p[ITEMS_A];
        int bkt[ITEMS_A], rnk[ITEMS_A];
        #pragma unroll
        for (int j = 0; j < ITEMS_A; ++j) {
            int i = base + j * TA_THREADS + tid;
            bkt[j] = -1;
            if (i < NRECS) {
                int row; unsigned long long pay;
                if (i < N_EDGES) {
                    row = head[i];
                    pay = ((unsigned long long)(unsigned)(etype[i] - 1) << 18) | (unsigned)tail[i];
                } else {
                    int jj = i - N_EDGES;
                    row = USR0 + irow[jj];
                    pay = ((unsigned long long)__float_as_uint(val[jj]) << 18) | (unsigned)icol[jj];
                }
                p[j] = pay | ((unsigned long long)(unsigned)(row & (BROWS - 1)) << 50);
                bkt[j] = row >> 10;
                rnk[j] = atomicAdd(&cntS[bkt[j]], 1);
            }
        }
        __syncthreads();
        if (tid == 0) {
            int s = 0;
            for (int b = 0; b < NB; ++b) { startS[b] = s; s += cntS[b]; }
        }
        __syncthreads();
        if (tid < NB && cntS[tid] > 0)
            gbase[tid] = tid * RCAP + atomicAdd(&bcur[tid], cntS[tid]);
        __syncthreads();

        #pragma unroll
        for (int j = 0; j < ITEMS_A; ++j) {
            if (bkt[j] >= 0) {
                int s = startS[bkt[j]] + rnk[j];
                buf[s] = p[j];
                bk[s] = (unsigned short)bkt[j];
            }
        }
        __syncthreads();

        int total = startS[NB - 1] + cntS[NB - 1];
        for (int s = tid; s < total; s += TA_THREADS) {
            int b = bk[s];
            int dst = gbase[b] + (s - startS[b]);
            if (dst < (b + 1) * RCAP) binned[dst] = buf[s];   // overflow guard (never triggers)
        }
    } else if (blk == BIN_BLOCKS) {
        // ---- prep: disenw + cor ----
        if (tid < 256) {
            int f  = tid >> 6;
            int ch = tid & 63;
            float m = -1e30f;
            for (int r = 0; r < N_RELM1; ++r) m = fmaxf(m, att[f * N_RELM1 + r]);
            float ex[N_RELM1];
            float s = 0.f;
            for (int r = 0; r < N_RELM1; ++r) { ex[r] = expf(att[f * N_RELM1 + r] - m); s += ex[r]; }
            float inv = 1.f / s;
            float acc = 0.f;
            for (int r = 0; r < N_RELM1; ++r) acc += (ex[r] * inv) * weight[r * CHN + ch];
            disenw[f * CHN + ch] = acc;
        }
        if (tid == 0) {
            float wn[N_FACTORS][N_RELM1];
            for (int i = 0; i < N_FACTORS; ++i) {
                float ss = 0.f;
                for (int r = 0; r < N_RELM1; ++r) { float v = att[i * N_RELM1 + r]; ss += v * v; }
                float innv = 1.f / sqrtf(ss);
                for (int r = 0; r < N_RELM1; ++r) wn[i][r] = att[i * N_RELM1 + r] * innv;
            }
            float cor = 0.f;
            for (int i = 0; i < N_FACTORS; ++i)
                for (int j = i + 1; j < N_FACTORS; ++j) {
                    float d = 0.f;
                    for (int r = 0; r < N_RELM1; ++r) d += wn[i][r] * wn[j][r];
                    cor += d * d;
                }
            cor_out[0] = cor;
        }
    } else {
        // ---- bf16 conversion of entity table ----
        int i = (blk - BIN_BLOCKS - 1) * 512 + tid;
        if (i < CONV_N4) {
            float4 v = esrc[i];
            ebf0[i] = make_ushort4(f2bf(v.x), f2bf(v.y), f2bf(v.z), f2bf(v.w));
        }
    }
}

// -------------------- Pass B: per-bucket local CSR; emits 16B row headers ----
// headerE[row] = {cnt<<22|offs, rec0, rec1, rec2}
// headerU[row] = {cnt<<22|offs, rec0.lo, rec0.hi, 0}
__global__ __launch_bounds__(512) void bucket_scatter_kernel(
    const unsigned long long* __restrict__ binned,
    const int* __restrict__ bcur,
    unsigned int* __restrict__ recsE,
    unsigned long long* __restrict__ recsU,
    uint4* __restrict__ headerE,
    uint4* __restrict__ headerU)
{
    __shared__ int rowcnt[BROWS];
    __shared__ int sExcl[BROWS];
    __shared__ int sA[512], sB[512];
    __shared__ unsigned int hdr0[BROWS], hdr1[BROWS], hdr2[BROWS];

    int tid = threadIdx.x;
    int b = blockIdx.x;
    rowcnt[2 * tid] = 0;
    rowcnt[2 * tid + 1] = 0;
    hdr0[2 * tid] = 0; hdr0[2 * tid + 1] = 0;
    hdr1[2 * tid] = 0; hdr1[2 * tid + 1] = 0;
    hdr2[2 * tid] = 0; hdr2[2 * tid + 1] = 0;
    __syncthreads();

    int s0 = b * RCAP;
    int nrec = bcur[b];
    if (nrec > RCAP) nrec = RCAP;
    int s1 = s0 + nrec;

    // pass 1: per-row counts
    for (int i = s0 + tid; i < s1; i += 512) {
        int rowlo = (int)(binned[i] >> 50) & (BROWS - 1);
        atomicAdd(&rowcnt[rowlo], 1);
    }
    __syncthreads();

    int c0 = rowcnt[2 * tid];
    int c1 = rowcnt[2 * tid + 1];
    int pc0 = (c0 + 1) & ~1;               // pad to even
    int pc1 = (c1 + 1) & ~1;
    sA[tid] = pc0 + pc1;
    __syncthreads();
    int* src = sA; int* dst = sB;
    #pragma unroll
    for (int off = 1; off < 512; off <<= 1) {
        dst[tid] = src[tid] + ((tid >= off) ? src[tid - off] : 0);
        __syncthreads();
        int* tm = src; src = dst; dst = tm;
    }
    int excl = src[tid] - (pc0 + pc1);

    int gbaseOut = (b < EBUCKETS ? b : b - EBUCKETS) * RCAP_OUT;
    __syncthreads();
    rowcnt[2 * tid] = excl;                 // bucket-local cursors
    rowcnt[2 * tid + 1] = excl + pc0;
    sExcl[2 * tid] = excl;
    sExcl[2 * tid + 1] = excl + pc0;
    __syncthreads();

    // pass 2: scatter to final slots; capture first records for the header
    if (b < EBUCKETS) {
        for (int i = s0 + tid; i < s1; i += 512) {
            unsigned long long p = binned[i];
            int rowlo = (int)(p >> 50) & (BROWS - 1);
            int local = atomicAdd(&rowcnt[rowlo], 1);
            unsigned rec = (unsigned)(p & ((1ull << 50) - 1));
            recsE[gbaseOut + local] = rec;
            int rank = local - sExcl[rowlo];
            if (rank == 0) hdr0[rowlo] = rec;
            else if (rank == 1) hdr1[rowlo] = rec;
            else if (rank == 2) hdr2[rowlo] = rec;
        }
        __syncthreads();
        int grow = b * BROWS;
        #pragma unroll
        for (int t = 0; t < 2; ++t) {
            int r = 2 * tid + t;
            int row = grow + r;
            if (row < N_ENTITIES) {
                unsigned co = ((unsigned)((t == 0) ? c0 : c1) << 22) |
                              (unsigned)(gbaseOut + sExcl[r]);
                headerE[row] = make_uint4(co, hdr0[r], hdr1[r], hdr2[r]);
            }
        }
    } else {
        for (int i = s0 + tid; i < s1; i += 512) {
            unsigned long long p = binned[i];
            int rowlo = (int)(p >> 50) & (BROWS - 1);
            int local = atomicAdd(&rowcnt[rowlo], 1);
            unsigned long long rec = p & ((1ull << 50) - 1);
            recsU[gbaseOut + local] = rec;
            int rank = local - sExcl[rowlo];
            if (rank == 0) { hdr0[rowlo] = (unsigned)rec; hdr1[rowlo] = (unsigned)(rec >> 32); }
        }
        __syncthreads();
        int grow = b * BROWS - USR0;
        #pragma unroll
        for (int t = 0; t < 2; ++t) {
            int r = 2 * tid + t;
            int urow = grow + r;
            if (urow >= 0 && urow < N_USERS) {
                unsigned co = ((unsigned)((t == 0) ? c0 : c1) << 22) |
                              (unsigned)(gbaseOut + sExcl[r]);
                headerU[urow] = make_uint4(co, hdr0[r], hdr1[r], 0u);
            }
        }
    }
}

// -------------------- fused hop: 8 lanes per row, 8 bf16 (uint4) per lane ------------
__device__ __forceinline__ void fma8w(uint4 g, const float* __restrict__ w, float* acc) {
    acc[0] += __uint_as_float(g.x << 16)          * w[0];
    acc[1] += __uint_as_float(g.x & 0xffff0000u)  * w[1];
    acc[2] += __uint_as_float(g.y << 16)          * w[2];
    acc[3] += __uint_as_float(g.y & 0xffff0000u)  * w[3];
    acc[4] += __uint_as_float(g.z << 16)          * w[4];
    acc[5] += __uint_as_float(g.z & 0xffff0000u)  * w[5];
    acc[6] += __uint_as_float(g.w << 16)          * w[6];
    acc[7] += __uint_as_float(g.w & 0xffff0000u)  * w[7];
}
__device__ __forceinline__ void fma8v(uint4 g, float v, float* acc) {
    acc[0] += __uint_as_float(g.x << 16)          * v;
    acc[1] += __uint_as_float(g.x & 0xffff0000u)  * v;
    acc[2] += __uint_as_float(g.y << 16)          * v;
    acc[3] += __uint_as_float(g.y & 0xffff0000u)  * v;
    acc[4] += __uint_as_float(g.z << 16)          * v;
    acc[5] += __uint_as_float(g.z & 0xffff0000u)  * v;
    acc[6] += __uint_as_float(g.w << 16)          * v;
    acc[7] += __uint_as_float(g.w & 0xffff0000u)  * v;
}
__device__ __forceinline__ void bf8_unpack(uint4 g, float* o) {
    o[0] = __uint_as_float(g.x << 16); o[1] = __uint_as_float(g.x & 0xffff0000u);
    o[2] = __uint_as_float(g.y << 16); o[3] = __uint_as_float(g.y & 0xffff0000u);
    o[4] = __uint_as_float(g.z << 16); o[5] = __uint_as_float(g.z & 0xffff0000u);
    o[6] = __uint_as_float(g.w << 16); o[7] = __uint_as_float(g.w & 0xffff0000u);
}

// PASS 1: gather from ebf0 -> write compact bf16 state only (ebfA, ubfA).
// PASS 2: gather from ebfA -> out = emb(f32) + y1(bf16, own-row) + y2.
template<int PASS>
__global__ __launch_bounds__(256) void hop_kernel(
    const unsigned short* __restrict__ ebf,     // gather table (pass1: ebf0, pass2: ebfA)
    const unsigned int* __restrict__ recsE,
    const unsigned long long* __restrict__ recsU,
    const uint4* __restrict__ headerE,
    const uint4* __restrict__ headerU,
    const float* __restrict__ weight,           // [16][64] f32
    const float* __restrict__ latent,           // [4][64]
    const float* __restrict__ disenw,           // [4][64]
    const float* __restrict__ u_emb,            // user_emb f32 (pass1: softmax src; pass2: base)
    const float* __restrict__ e_emb,            // entity_emb f32 (pass2 base)
    const unsigned short* __restrict__ ubfA,    // pass2: u1 bf16 (softmax src + residual term)
    unsigned short* __restrict__ ebf_new,       // pass1 out
    unsigned short* __restrict__ ubf_new,       // pass1 out
    float* __restrict__ out_ent,                // pass2 out
    float* __restrict__ out_usr)                // pass2 out
{
    __shared__ float wl[N_RELM1 * CHN];
    for (int k = threadIdx.x; k < N_RELM1 * CHN; k += 256) wl[k] = weight[k];
    __syncthreads();

    unsigned idx = blockIdx.x * 256u + threadIdx.x;
    unsigned row = idx >> 3;          // 8 lanes per row
    int sub = idx & 7;                // channels [sub*8, sub*8+8)
    int chb = sub * 8;

    float acc[8] = {0.f,0.f,0.f,0.f,0.f,0.f,0.f,0.f};

    if (row < N_ENTITIES) {
        uint4 h = headerE[row];
        int n = h.x >> 22;
        int start = h.x & 0x3FFFFF;
        // inline records: gathers issue right after the header arrives
        if (n > 0) {
            uint4 g = *(const uint4*)(ebf + (size_t)(h.y & 0x3FFFF) * CHN + chb);
            fma8w(g, &wl[(h.y >> 18) * CHN + chb], acc);
        }
        if (n > 1) {
            uint4 g = *(const uint4*)(ebf + (size_t)(h.z & 0x3FFFF) * CHN + chb);
            fma8w(g, &wl[(h.z >> 18) * CHN + chb], acc);
        }
        if (n > 2) {
            uint4 g = *(const uint4*)(ebf + (size_t)(h.w & 0x3FFFF) * CHN + chb);
            fma8w(g, &wl[(h.w >> 18) * CHN + chb], acc);
        }
        int k = 3;
        for (; k + 4 <= n; k += 4) {
            unsigned r0 = recsE[start + k];
            unsigned r1 = recsE[start + k + 1];
            unsigned r2 = recsE[start + k + 2];
            unsigned r3 = recsE[start + k + 3];
            uint4 g0 = *(const uint4*)(ebf + (size_t)(r0 & 0x3FFFF) * CHN + chb);
            uint4 g1 = *(const uint4*)(ebf + (size_t)(r1 & 0x3FFFF) * CHN + chb);
            uint4 g2 = *(const uint4*)(ebf + (size_t)(r2 & 0x3FFFF) * CHN + chb);
            uint4 g3 = *(const uint4*)(ebf + (size_t)(r3 & 0x3FFFF) * CHN + chb);
            fma8w(g0, &wl[(r0 >> 18) * CHN + chb], acc);
            fma8w(g1, &wl[(r1 >> 18) * CHN + chb], acc);
            fma8w(g2, &wl[(r2 >> 18) * CHN + chb], acc);
            fma8w(g3, &wl[(r3 >> 18) * CHN + chb], acc);
        }
        for (; k < n; ++k) {
            unsigned r0 = recsE[start + k];
            uint4 g0 = *(const uint4*)(ebf + (size_t)(r0 & 0x3FFFF) * CHN + chb);
            fma8w(g0, &wl[(r0 >> 18) * CHN + chb], acc);
        }
        float inv_d = (n > 0) ? (1.f / (float)n) : 1.f;
        float ss = 0.f;
        #pragma unroll
        for (int i = 0; i < 8; ++i) { acc[i] *= inv_d; ss += acc[i] * acc[i]; }
        ss += __shfl_xor(ss, 1, 64);
        ss += __shfl_xor(ss, 2, 64);
        ss += __shfl_xor(ss, 4, 64);
        float innv = 1.f / fmaxf(sqrtf(ss), 1e-12f);
        float y[8];
        #pragma unroll
        for (int i = 0; i < 8; ++i) y[i] = acc[i] * innv;
        if (PASS == 1) {
            uint4 pk;
            pk.x = (unsigned)f2bf(y[0]) | ((unsigned)f2bf(y[1]) << 16);
            pk.y = (unsigned)f2bf(y[2]) | ((unsigned)f2bf(y[3]) << 16);
            pk.z = (unsigned)f2bf(y[4]) | ((unsigned)f2bf(y[5]) << 16);
            pk.w = (unsigned)f2bf(y[6]) | ((unsigned)f2bf(y[7]) << 16);
            *(uint4*)(ebf_new + (size_t)row * CHN + chb) = pk;
        } else {
            float y1[8];
            bf8_unpack(*(const uint4*)(ebf + (size_t)row * CHN + chb), y1);  // own hop-1 value
            const vf4* bp = (const vf4*)&e_emb[(size_t)row * CHN + chb];
            vf4 b0 = __builtin_nontemporal_load(bp);
            vf4 b1 = __builtin_nontemporal_load(bp + 1);
            vf4* op = (vf4*)&out_ent[(size_t)row * CHN + chb];
            vf4 o0 = {b0.x + y1[0] + y[0], b0.y + y1[1] + y[1], b0.z + y1[2] + y[2], b0.w + y1[3] + y[3]};
            vf4 o1 = {b1.x + y1[4] + y[4], b1.y + y1[5] + y[5], b1.z + y1[6] + y[6], b1.w + y1[7] + y[7]};
            __builtin_nontemporal_store(o0, op);
            __builtin_nontemporal_store(o1, op + 1);
        }
    } else if (row >= USR0 && row < ROWS_EFF) {
        unsigned ur = row - USR0;
        uint4 h = headerU[ur];
        int n = h.x >> 22;
        int start = h.x & 0x3FFFFF;

        // inline record 0 gathers immediately
        if (n > 0) {
            unsigned long long q = ((unsigned long long)h.z << 32) | h.y;
            uint4 g = *(const uint4*)(ebf + (size_t)(q & 0x3FFFFu) * CHN + chb);
            fma8v(g, __uint_as_float((unsigned)(q >> 18)), acc);
        }
        int k = 1;
        for (; k + 4 <= n; k += 4) {
            unsigned long long q0 = recsU[start + k];
            unsigned long long q1 = recsU[start + k + 1];
            unsigned long long q2 = recsU[start + k + 2];
            unsigned long long q3 = recsU[start + k + 3];
            uint4 g0 = *(const uint4*)(ebf + (size_t)(q0 & 0x3FFFFu) * CHN + chb);
            uint4 g1 = *(const uint4*)(ebf + (size_t)(q1 & 0x3FFFFu) * CHN + chb);
            uint4 g2 = *(const uint4*)(ebf + (size_t)(q2 & 0x3FFFFu) * CHN + chb);
            uint4 g3 = *(const uint4*)(ebf + (size_t)(q3 & 0x3FFFFu) * CHN + chb);
            fma8v(g0, __uint_as_float((unsigned)(q0 >> 18)), acc);
            fma8v(g1, __uint_as_float((unsigned)(q1 >> 18)), acc);
            fma8v(g2, __uint_as_float((unsigned)(q2 >> 18)), acc);
            fma8v(g3, __uint_as_float((unsigned)(q3 >> 18)), acc);
        }
        for (; k < n; ++k) {
            unsigned long long q0 = recsU[start + k];
            uint4 g0 = *(const uint4*)(ebf + (size_t)(q0 & 0x3FFFFu) * CHN + chb);
            fma8v(g0, __uint_as_float((unsigned)(q0 >> 18)), acc);
        }

        float uo[8];
        if (PASS == 1) {
            const float4* up = (const float4*)&u_emb[(size_t)ur * CHN + chb];
            float4 a0 = up[0], a1 = up[1];
            uo[0]=a0.x; uo[1]=a0.y; uo[2]=a0.z; uo[3]=a0.w;
            uo[4]=a1.x; uo[5]=a1.y; uo[6]=a1.z; uo[7]=a1.w;
        } else {
            bf8_unpack(*(const uint4*)(ubfA + (size_t)ur * CHN + chb), uo);
        }

        float dotv[N_FACTORS];
        #pragma unroll
        for (int f = 0; f < N_FACTORS; ++f) {
            const float4* lp = (const float4*)&latent[f * CHN + chb];
            float4 l0 = lp[0], l1 = lp[1];
            float p = uo[0] * l0.x + uo[1] * l0.y + uo[2] * l0.z + uo[3] * l0.w
                    + uo[4] * l1.x + uo[5] * l1.y + uo[6] * l1.z + uo[7] * l1.w;
            p += __shfl_xor(p, 1, 64);
            p += __shfl_xor(p, 2, 64);
            p += __shfl_xor(p, 4, 64);
            dotv[f] = p;
        }
        float m = fmaxf(fmaxf(dotv[0], dotv[1]), fmaxf(dotv[2], dotv[3]));
        float es = 0.f;
        #pragma unroll
        for (int f = 0; f < N_FACTORS; ++f) { dotv[f] = expf(dotv[f] - m); es += dotv[f]; }
        float sinv = 1.f / es;
        float mix[8] = {0.f,0.f,0.f,0.f,0.f,0.f,0.f,0.f};
        #pragma unroll
        for (int f = 0; f < N_FACTORS; ++f) {
            float sc = dotv[f] * sinv;
            const float4* dp = (const float4*)&disenw[f * CHN + chb];
            float4 d0 = dp[0], d1 = dp[1];
            mix[0] += sc * d0.x; mix[1] += sc * d0.y; mix[2] += sc * d0.z; mix[3] += sc * d0.w;
            mix[4] += sc * d1.x; mix[5] += sc * d1.y; mix[6] += sc * d1.z; mix[7] += sc * d1.w;
        }

        float ss = 0.f;
        #pragma unroll
        for (int i = 0; i < 8; ++i) { acc[i] *= (1.f + mix[i]); ss += acc[i] * acc[i]; }
        ss += __shfl_xor(ss, 1, 64);
        ss += __shfl_xor(ss, 2, 64);
        ss += __shfl_xor(ss, 4, 64);
        float innv = 1.f / fmaxf(sqrtf(ss), 1e-12f);
        float y[8];
        #pragma unroll
        for (int i = 0; i < 8; ++i) y[i] = acc[i] * innv;
        if (PASS == 1) {
            uint4 pk;
            pk.x = (unsigned)f2bf(y[0]) | ((unsigned)f2bf(y[1]) << 16);
            pk.y = (unsigned)f2bf(y[2]) | ((unsigned)f2bf(y[3]) << 16);
            pk.z = (unsigned)f2bf(y[4]) | ((unsigned)f2bf(y[5]) << 16);
            pk.w = (unsigned)f2bf(y[6]) | ((unsigned)f2bf(y[7]) << 16);
            *(uint4*)(ubf_new + (size_t)ur * CHN + chb) = pk;
        } else {
            const vf4* bp = (const vf4*)&u_emb[(size_t)ur * CHN + chb];
            vf4 b0 = __builtin_nontemporal_load(bp);
            vf4 b1 = __builtin_nontemporal_load(bp + 1);
            vf4* op = (vf4*)&out_usr[(size_t)ur * CHN + chb];
            vf4 o0 = {b0.x + uo[0] + y[0], b0.y + uo[1] + y[1], b0.z + uo[2] + y[2], b0.w + uo[3] + y[3]};
            vf4 o1 = {b1.x + uo[4] + y[4], b1.y + uo[5] + y[5], b1.z + uo[6] + y[6], b1.w + uo[7] + y[7]};
            __builtin_nontemporal_store(o0, op);
            __builtin_nontemporal_store(o1, op + 1);
        }
    }
}

extern "C" void kernel_launch(void* const* d_in, const int* in_sizes, int n_in,
                              void* d_out, int out_size, void* d_ws, size_t ws_size,
                              hipStream_t stream) {
    const float* user_emb   = (const float*)d_in[0];
    const float* entity_emb = (const float*)d_in[1];
    const float* latent_emb = (const float*)d_in[2];
    const float* weight     = (const float*)d_in[3];
    const float* att        = (const float*)d_in[4];
    const float* inter_val  = (const float*)d_in[5];
    const int*   edge_index = (const int*)d_in[6];   // [2][N_EDGES]
    const int*   edge_type  = (const int*)d_in[7];
    const int*   inter_row  = (const int*)d_in[8];
    const int*   inter_col  = (const int*)d_in[9];

    const int* head = edge_index;
    const int* tail = edge_index + N_EDGES;

    float* out_ent = (float*)d_out;                              // [250000*64]
    float* out_usr = out_ent + (size_t)N_ENTITIES * CHN;         // [150000*64]
    float* out_cor = out_usr + (size_t)N_USERS * CHN;            // [1]

    // workspace layout (byte offsets kept 16B-aligned)
    char* ws = (char*)d_ws;
    unsigned short* ebf0   = (unsigned short*)ws;                             // 32,000,000 B
    unsigned short* ebfA   = (unsigned short*)(ws + 32000000);                // 32,000,000 B
    unsigned short* ubfA   = (unsigned short*)(ws + 64000000);                // 19,200,000 B
    unsigned long long* binned = (unsigned long long*)(ws + 83200000);        // NB*RCAP u64 = 25,690,112 B
    unsigned long long* recsU  = (unsigned long long*)(ws + 108890112);       // 147*RCAP_OUT u64 = 9,633,792 B
    unsigned int* recsE    = (unsigned int*)(ws + 118523904);                 // 245*RCAP_OUT u32 = 8,028,160 B
    float* disenw          = (float*)(ws + 126552064);                        // 1,024 B
    uint4* headerE         = (uint4*)(ws + 126553088);                        // 250000*16 = 4,000,000 B
    uint4* headerU         = (uint4*)(ws + 130553088);                        // 150000*16 = 2,400,000 B
    int*   bcur            = (int*)(ws + 132953088);                          // NB i

    // ---- bucket cursors = 0 (offset-from-base scheme) ----
    hipMemsetAsync(bcur, 0, NB * sizeof(int), stream);

    // ---- fused build: bin_pass + prep + bf16 conv ----
    build_kernel<<<BIN_BLOCKS + 1 + CONV_BLOCKS, 512, 0, stream>>>(
        head, tail, edge_type, inter_row, inter_col, inter_val,
        bcur, binned, weight, att, disenw, out_cor,
        (const float4*)entity_emb, (ushort4*)ebf0);

    // ---- per-bucket CSR + headers ----
    bucket_scatter_kernel<<<NB, 512, 0, stream>>>(binned, bcur, recsE, recsU,
                                                  headerE, headerU);

    const int hop_blocks = (ROWS_EFF * 8 + 255) / 256;           // 12528

    // ---- hop 1: gather from ebf0 -> compact bf16 state (ebfA, ubfA) ----
    hop_kernel<1><<<hop_blocks, 256, 0, stream>>>(ebf0, recsE, recsU, headerE, headerU,
                                                  weight, latent_emb, disenw,
                                                  user_emb, entity_emb, nullptr,
                                                  ebfA, ubfA, nullptr, nullptr);

    // ---- hop 2: gather from ebfA -> out = emb + y1 + y2 ----
    hop_kernel<2><<<hop_blocks, 256, 0, stream>>>(ebfA, recsE, recsU, headerE, headerU,
                                                  weight, latent_emb, disenw,
                                                  user_emb, entity_emb, ubfA,
                                                  nullptr, nullptr, out_ent, out_usr);
}